// Round 9
// baseline (1980.739 us; speedup 1.0000x reference)
//
#include <hip/hip_runtime.h>
#include <math.h>

#define EPSV 1e-4f
#define NSWEEP 10
#define NRTB (49 * NSWEEP)
#define SKIPTH 1e-9f

// ---------- 16-lane all-reduce sum on the VALU (DPP), no LDS pipe ----------
template <int CTRL>
__device__ __forceinline__ float dppadd(float x) {
  int y = __builtin_amdgcn_update_dpp(0, __float_as_int(x), CTRL, 0xF, 0xF, false);
  return x + __int_as_float(y);
}
__device__ __forceinline__ float sum16(float x) {
  x = dppadd<0xB1>(x);   // quad_perm [1,0,3,2]  == xor 1
  x = dppadd<0x4E>(x);   // quad_perm [2,3,0,1]  == xor 2
  x = dppadd<0x124>(x);  // row_ror:4
  x = dppadd<0x128>(x);  // row_ror:8
  return x;
}

// one Jacobi rotation on a register-resident column pair (group-uniform)
__device__ __forceinline__ bool rot_pair(float4& xa, float4& ya, float& na,
                                         float4& xb, float4& yb, float& nb) {
  float d = xa.x * xb.x + xa.y * xb.y + xa.z * xb.z + xa.w * xb.w
          + ya.x * yb.x + ya.y * yb.y + ya.z * yb.z + ya.w * yb.w;
  d = sum16(d);
  const bool rot = (d * d > SKIPTH * na * nb + 1e-30f);
  float tau = (nb - na) / (2.f * d);
  float t = copysignf(1.f, tau) / (fabsf(tau) + sqrtf(1.f + tau * tau));
  float c = 1.f / sqrtf(1.f + t * t);
  float s = t * c;
  c = rot ? c : 1.f;          // selects kill any NaN from d==0 path
  s = rot ? s : 0.f;
  float td = rot ? t * d : 0.f;
  float4 u, v;
  u.x = c * xa.x - s * xb.x; u.y = c * xa.y - s * xb.y;
  u.z = c * xa.z - s * xb.z; u.w = c * xa.w - s * xb.w;
  v.x = s * xa.x + c * xb.x; v.y = s * xa.y + c * xb.y;
  v.z = s * xa.z + c * xb.z; v.w = s * xa.w + c * xb.w;
  xa = u; xb = v;
  u.x = c * ya.x - s * yb.x; u.y = c * ya.y - s * yb.y;
  u.z = c * ya.z - s * yb.z; u.w = c * ya.w - s * yb.w;
  v.x = s * ya.x + c * yb.x; v.y = s * ya.y + c * yb.y;
  v.z = s * ya.z + c * yb.z; v.w = s * ya.w + c * yb.w;
  ya = u; yb = v;
  na -= td; nb += td;
  return rot;
}

// ---------- Kernel A: W = W1 @ W2 (400x200 @ 200x100 -> 400x100) ----------
__global__ __launch_bounds__(256) void kA(const float* __restrict__ W1,
                                          const float* __restrict__ W2,
                                          float* __restrict__ W) {
  int e = blockIdx.x * 256 + threadIdx.x;
  if (e >= 400 * 100) return;
  int i = e / 100, j = e - (e / 100) * 100;
  float s = 0.f;
#pragma unroll 4
  for (int k = 0; k < 200; ++k) s += W1[i * 200 + k] * W2[k * 100 + j];
  W[e] = s;
}

// ---------- Kernel B: Y[b] = x[b] @ W  (400x400 @ 400x100) ----------
__global__ __launch_bounds__(256) void kB(const float* __restrict__ x,
                                          const float* __restrict__ W,
                                          float* __restrict__ Y) {
  __shared__ float xs[16][41];
  __shared__ float ws[40][104];
  const int b = blockIdx.y, rt = blockIdx.x;
  const int tid = threadIdx.x;
  const int tc = tid & 31, tr = tid >> 5;
  const float* xb = x + (size_t)b * 160000 + (size_t)rt * 16 * 400;
  float acc[2][4] = {{0.f, 0.f, 0.f, 0.f}, {0.f, 0.f, 0.f, 0.f}};
  for (int k0 = 0; k0 < 400; k0 += 40) {
    for (int e = tid; e < 640; e += 256) {
      int r = e / 40, kk = e - r * 40;
      xs[r][kk] = xb[r * 400 + k0 + kk];
    }
    for (int e = tid; e < 4000; e += 256) {
      int kk = e / 100, j = e - kk * 100;
      ws[kk][j] = W[(k0 + kk) * 100 + j];
    }
    __syncthreads();
#pragma unroll 8
    for (int kk = 0; kk < 40; ++kk) {
      float a0 = xs[tr][kk], a1 = xs[tr + 8][kk];
      float b0 = ws[kk][tc], b1 = ws[kk][tc + 32], b2 = ws[kk][tc + 64];
      float b3 = (tc + 96 < 100) ? ws[kk][tc + 96] : 0.f;
      acc[0][0] += a0 * b0; acc[0][1] += a0 * b1; acc[0][2] += a0 * b2; acc[0][3] += a0 * b3;
      acc[1][0] += a1 * b0; acc[1][1] += a1 * b1; acc[1][2] += a1 * b2; acc[1][3] += a1 * b3;
    }
    __syncthreads();
  }
  float* Yb = Y + (size_t)b * 40000 + (size_t)rt * 1600;
#pragma unroll
  for (int rr = 0; rr < 2; ++rr) {
    int r = tr + 8 * rr;
#pragma unroll
    for (int u = 0; u < 4; ++u) {
      int c = tc + 32 * u;
      if (c < 100) Yb[r * 100 + c] = acc[rr][u];
    }
  }
}

// flat triu index (n=100) -> row (one-off use in symmetrize)
__device__ __forceinline__ int triu_row(int e) {
  int i = (int)((201.0f - sqrtf(40401.0f - 8.0f * (float)e)) * 0.5f);
  if (i < 0) i = 0;
  if (i > 99) i = 99;
  while (i > 0 && (201 * i - i * i) > 2 * e) --i;
  while ((201 * (i + 1) - (i + 1) * (i + 1)) <= 2 * e) ++i;
  return i;
}

// ---------- Kernel C: M = W^T Y_b ; logm via one-sided BLOCK Jacobi ; classifier ----------
__global__ __launch_bounds__(1024) void kC(const float* __restrict__ W,
                                           const float* __restrict__ Y,
                                           const float* __restrict__ Wc,
                                           const float* __restrict__ bcv,
                                           float* __restrict__ out) {
  __shared__ float B[10000];      // column-major: column p at B + p*100
  __shared__ float stage[8320];   // GEMM staging; later Hf[5050]
  __shared__ float nrm[100];      // maintained squared column norms
  __shared__ float sfin[100];
  __shared__ float red[16][12];
  __shared__ int rotflag[25];
  __shared__ int brk;

  const int b = blockIdx.x, tid = threadIdx.x;
  const int q4 = tid & 31;
  const int r32 = tid >> 5;
  const int g = tid >> 4, lane = tid & 15;  // 64 groups of 16 (row-aligned for DPP)

  // ---- M = W^T @ Y_b  into B ----
  {
    float* Wst = stage;          // [40][104]
    float* Yst = stage + 4160;   // [40][104]
    const float* Yb = Y + (size_t)b * 40000;
    float acc[4][4];
#pragma unroll
    for (int m = 0; m < 4; ++m) acc[m][0] = acc[m][1] = acc[m][2] = acc[m][3] = 0.f;
    for (int k0 = 0; k0 < 400; k0 += 40) {
      for (int e = tid; e < 4000; e += 1024) {
        int kk = e / 100, j = e - kk * 100;
        Wst[kk * 104 + j] = W[(k0 + kk) * 100 + j];
        Yst[kk * 104 + j] = Yb[(k0 + kk) * 100 + j];
      }
      __syncthreads();
      for (int kk = 0; kk < 40; ++kk) {
        float y0 = Yst[kk * 104 + q4], y1 = Yst[kk * 104 + q4 + 32], y2 = Yst[kk * 104 + q4 + 64];
        float y3 = (q4 + 96 < 100) ? Yst[kk * 104 + q4 + 96] : 0.f;
#pragma unroll
        for (int m = 0; m < 4; ++m) {
          int p = r32 + 32 * m;
          if (p < 100) {
            float w = Wst[kk * 104 + p];
            acc[m][0] += w * y0; acc[m][1] += w * y1; acc[m][2] += w * y2; acc[m][3] += w * y3;
          }
        }
      }
      __syncthreads();
    }
#pragma unroll
    for (int m = 0; m < 4; ++m) {
      int p = r32 + 32 * m;
      if (p < 100) {
        B[p * 100 + q4] = acc[m][0];
        B[p * 100 + q4 + 32] = acc[m][1];
        B[p * 100 + q4 + 64] = acc[m][2];
        if (q4 + 96 < 100) B[p * 100 + q4 + 96] = acc[m][3];
      }
    }
  }
  if (tid < 25) rotflag[tid] = 0;
  __syncthreads();
  // symmetrize both triangles
  for (int e = tid; e < 5050; e += 1024) {
    int i = triu_row(e);
    int j = i + (e - ((201 * i - i * i) >> 1));
    float av = 0.5f * (B[i * 100 + j] + B[j * 100 + i]);
    B[i * 100 + j] = av;
    B[j * 100 + i] = av;
  }
  __syncthreads();
  // initial squared norms (group g covers columns g, g+64)
  for (int col = g; col < 100; col += 64) {
    const float* bp = B + col * 100;
    float4 a4 = *(const float4*)(bp + 4 * lane);
    float n = a4.x * a4.x + a4.y * a4.y + a4.z * a4.z + a4.w * a4.w;
    if (lane < 9) {
      float4 a8 = *(const float4*)(bp + 64 + 4 * lane);
      n += a8.x * a8.x + a8.y * a8.y + a8.z * a8.z + a8.w * a8.w;
    }
    n = sum16(n);
    if (lane == 0) nrm[col] = n;
  }
  __syncthreads();

  // ---- one-sided BLOCK Jacobi: 50 blocks of 2 cols, circle tournament ----
  // group g handles block pair (bi,bj): 4 columns register-resident,
  // mini-sweep of 6 rotations {01,23},{02,13},{03,12}, write back once.
  for (int r = 0; r < NRTB; ++r) {
    const int rr = r % 49;
    if (g < 25) {
      int bi, bj;
      if (g == 0) { bi = 49; bj = rr; }
      else {
        bi = rr + g; if (bi >= 49) bi -= 49;
        bj = rr - g; if (bj < 0) bj += 49;
      }
      float* p0 = B + (2 * bi) * 100;
      float* p1 = B + (2 * bi + 1) * 100;
      float* p2 = B + (2 * bj) * 100;
      float* p3 = B + (2 * bj + 1) * 100;
      float4 x0 = *(const float4*)(p0 + 4 * lane);
      float4 x1 = *(const float4*)(p1 + 4 * lane);
      float4 x2 = *(const float4*)(p2 + 4 * lane);
      float4 x3 = *(const float4*)(p3 + 4 * lane);
      float4 z = make_float4(0.f, 0.f, 0.f, 0.f);
      float4 y0 = z, y1 = z, y2 = z, y3 = z;
      if (lane < 9) {
        y0 = *(const float4*)(p0 + 64 + 4 * lane);
        y1 = *(const float4*)(p1 + 64 + 4 * lane);
        y2 = *(const float4*)(p2 + 64 + 4 * lane);
        y3 = *(const float4*)(p3 + 64 + 4 * lane);
      }
      float n0 = nrm[2 * bi], n1 = nrm[2 * bi + 1];
      float n2 = nrm[2 * bj], n3 = nrm[2 * bj + 1];
      bool any = false;
      // mini-round A: (0,1) (2,3)
      any |= rot_pair(x0, y0, n0, x1, y1, n1);
      any |= rot_pair(x2, y2, n2, x3, y3, n3);
      // mini-round B: (0,2) (1,3)
      any |= rot_pair(x0, y0, n0, x2, y2, n2);
      any |= rot_pair(x1, y1, n1, x3, y3, n3);
      // mini-round C: (0,3) (1,2)
      any |= rot_pair(x0, y0, n0, x3, y3, n3);
      any |= rot_pair(x1, y1, n1, x2, y2, n2);
      if (any) {  // group-uniform; identity rounds write nothing
        *(float4*)(p0 + 4 * lane) = x0;
        *(float4*)(p1 + 4 * lane) = x1;
        *(float4*)(p2 + 4 * lane) = x2;
        *(float4*)(p3 + 4 * lane) = x3;
        if (lane < 9) {
          *(float4*)(p0 + 64 + 4 * lane) = y0;
          *(float4*)(p1 + 64 + 4 * lane) = y1;
          *(float4*)(p2 + 64 + 4 * lane) = y2;
          *(float4*)(p3 + 64 + 4 * lane) = y3;
        }
        if (lane == 0) {
          nrm[2 * bi] = n0; nrm[2 * bi + 1] = n1;
          nrm[2 * bj] = n2; nrm[2 * bj + 1] = n3;
          rotflag[g] = 1;
        }
      }
    }
    __syncthreads();
    if (rr == 48) {  // sweep end: OR flags, clear, maybe break
      if (tid < 64) {
        int v = (tid < 25) ? rotflag[tid] : 0;
#pragma unroll
        for (int off = 32; off > 0; off >>= 1) v += __shfl_xor(v, off);
        if (tid == 0) brk = (v == 0) ? 1 : 0;
        if (tid < 25) rotflag[tid] = 0;
      }
      __syncthreads();
      if (brk) break;
    }
  }

  // ---- exact final scales: sfin[p] = log(max(||b_p||,EPSV)) / ||b_p||^2 ----
  for (int col = g; col < 100; col += 64) {
    const float* bp = B + col * 100;
    float4 a4 = *(const float4*)(bp + 4 * lane);
    float n = a4.x * a4.x + a4.y * a4.y + a4.z * a4.z + a4.w * a4.w;
    if (lane < 9) {
      float4 a8 = *(const float4*)(bp + 64 + 4 * lane);
      n += a8.x * a8.x + a8.y * a8.y + a8.z * a8.z + a8.w * a8.w;
    }
    n = sum16(n);
    if (lane == 0) sfin[col] = logf(fmaxf(sqrtf(n), EPSV)) / n;
  }
  __syncthreads();

  // ---- Hf (triu flat) = sum_p sfin[p] * b_p b_p^T ----
  float* Hf = stage;
  {
    float hacc[4][4];
#pragma unroll
    for (int m = 0; m < 4; ++m) hacc[m][0] = hacc[m][1] = hacc[m][2] = hacc[m][3] = 0.f;
    for (int p = 0; p < 100; ++p) {
      float l = sfin[p];
      const float* vr = B + p * 100;
      float vj0 = vr[q4], vj1 = vr[q4 + 32], vj2 = vr[q4 + 64];
      float vj3 = (q4 + 96 < 100) ? vr[q4 + 96] : 0.f;
#pragma unroll
      for (int m = 0; m < 4; ++m) {
        int i = r32 + 32 * m;
        if (i < 100) {
          float vil = vr[i] * l;
          hacc[m][0] += vil * vj0; hacc[m][1] += vil * vj1;
          hacc[m][2] += vil * vj2; hacc[m][3] += vil * vj3;
        }
      }
    }
    __syncthreads();
#pragma unroll
    for (int m = 0; m < 4; ++m) {
      int i = r32 + 32 * m;
      if (i >= 100) continue;
#pragma unroll
      for (int n = 0; n < 4; ++n) {
        int j = q4 + 32 * n;
        if (j < 100 && i <= j) Hf[((201 * i - i * i) >> 1) + (j - i)] = hacc[m][n];
      }
    }
  }
  __syncthreads();

  // ---- classifier ----
  float accc[10];
#pragma unroll
  for (int c = 0; c < 10; ++c) accc[c] = 0.f;
  for (int e = tid; e < 5050; e += 1024) {
    float h = Hf[e];
#pragma unroll
    for (int c = 0; c < 10; ++c) accc[c] += h * Wc[c * 5050 + e];
  }
  const int lane64 = tid & 63, wv = tid >> 6;
#pragma unroll
  for (int c = 0; c < 10; ++c) {
    float v = accc[c];
#pragma unroll
    for (int off = 32; off > 0; off >>= 1) v += __shfl_down(v, off);
    if (lane64 == 0) red[wv][c] = v;
  }
  __syncthreads();
  if (tid < 10) {
    float s = bcv[tid];
#pragma unroll
    for (int w = 0; w < 16; ++w) s += red[w][tid];
    out[b * 10 + tid] = s;
  }
}

extern "C" void kernel_launch(void* const* d_in, const int* in_sizes, int n_in,
                              void* d_out, int out_size, void* d_ws, size_t ws_size,
                              hipStream_t stream) {
  const float* x = (const float*)d_in[0];
  const float* W1 = (const float*)d_in[1];
  const float* W2 = (const float*)d_in[2];
  const float* Wc = (const float*)d_in[3];
  const float* bc = (const float*)d_in[4];
  float* out = (float*)d_out;

  float* W = (float*)d_ws;        // 400*100 floats
  float* Y = W + 40000;           // 256*400*100 floats (~41 MB)

  kA<<<157, 256, 0, stream>>>(W1, W2, W);
  kB<<<dim3(25, 256), 256, 0, stream>>>(x, W, Y);
  kC<<<256, 1024, 0, stream>>>(W, Y, Wc, bc, out);
}

// Round 10
// 1375.392 us; speedup vs baseline: 1.4401x; 1.4401x over previous
//
#include <hip/hip_runtime.h>
#include <math.h>

#define EPSV 1e-4f
#define NSWEEP 10
#define NRT (99 * NSWEEP)
#define SKIPTH 1e-9f

// ---------- 16-lane all-reduce sum on the VALU (DPP), no LDS pipe ----------
template <int CTRL>
__device__ __forceinline__ float dppadd(float x) {
  int y = __builtin_amdgcn_update_dpp(0, __float_as_int(x), CTRL, 0xF, 0xF, false);
  return x + __int_as_float(y);
}
__device__ __forceinline__ float sum16(float x) {
  x = dppadd<0xB1>(x);   // quad_perm [1,0,3,2]  == xor 1
  x = dppadd<0x4E>(x);   // quad_perm [2,3,0,1]  == xor 2
  x = dppadd<0x124>(x);  // row_ror:4
  x = dppadd<0x128>(x);  // row_ror:8
  return x;
}

// ---------- Kernel A: W = W1 @ W2 (400x200 @ 200x100 -> 400x100) ----------
__global__ __launch_bounds__(256) void kA(const float* __restrict__ W1,
                                          const float* __restrict__ W2,
                                          float* __restrict__ W) {
  int e = blockIdx.x * 256 + threadIdx.x;
  if (e >= 400 * 100) return;
  int i = e / 100, j = e - (e / 100) * 100;
  float s = 0.f;
#pragma unroll 4
  for (int k = 0; k < 200; ++k) s += W1[i * 200 + k] * W2[k * 100 + j];
  W[e] = s;
}

// ---------- Kernel B: Y[b] = x[b] @ W  (400x400 @ 400x100) ----------
__global__ __launch_bounds__(256) void kB(const float* __restrict__ x,
                                          const float* __restrict__ W,
                                          float* __restrict__ Y) {
  __shared__ float xs[16][41];
  __shared__ float ws[40][104];
  const int b = blockIdx.y, rt = blockIdx.x;
  const int tid = threadIdx.x;
  const int tc = tid & 31, tr = tid >> 5;
  const float* xb = x + (size_t)b * 160000 + (size_t)rt * 16 * 400;
  float acc[2][4] = {{0.f, 0.f, 0.f, 0.f}, {0.f, 0.f, 0.f, 0.f}};
  for (int k0 = 0; k0 < 400; k0 += 40) {
    for (int e = tid; e < 640; e += 256) {
      int r = e / 40, kk = e - r * 40;
      xs[r][kk] = xb[r * 400 + k0 + kk];
    }
    for (int e = tid; e < 4000; e += 256) {
      int kk = e / 100, j = e - kk * 100;
      ws[kk][j] = W[(k0 + kk) * 100 + j];
    }
    __syncthreads();
#pragma unroll 8
    for (int kk = 0; kk < 40; ++kk) {
      float a0 = xs[tr][kk], a1 = xs[tr + 8][kk];
      float b0 = ws[kk][tc], b1 = ws[kk][tc + 32], b2 = ws[kk][tc + 64];
      float b3 = (tc + 96 < 100) ? ws[kk][tc + 96] : 0.f;
      acc[0][0] += a0 * b0; acc[0][1] += a0 * b1; acc[0][2] += a0 * b2; acc[0][3] += a0 * b3;
      acc[1][0] += a1 * b0; acc[1][1] += a1 * b1; acc[1][2] += a1 * b2; acc[1][3] += a1 * b3;
    }
    __syncthreads();
  }
  float* Yb = Y + (size_t)b * 40000 + (size_t)rt * 1600;
#pragma unroll
  for (int rr = 0; rr < 2; ++rr) {
    int r = tr + 8 * rr;
#pragma unroll
    for (int u = 0; u < 4; ++u) {
      int c = tc + 32 * u;
      if (c < 100) Yb[r * 100 + c] = acc[rr][u];
    }
  }
}

// flat triu index (n=100) -> row (one-off use in symmetrize)
__device__ __forceinline__ int triu_row(int e) {
  int i = (int)((201.0f - sqrtf(40401.0f - 8.0f * (float)e)) * 0.5f);
  if (i < 0) i = 0;
  if (i > 99) i = 99;
  while (i > 0 && (201 * i - i * i) > 2 * e) --i;
  while ((201 * (i + 1) - (i + 1) * (i + 1)) <= 2 * e) ++i;
  return i;
}

// ---------- Kernel C: M = W^T Y_b ; logm via ONE-SIDED Jacobi (fused, DPP, sweep-skip) ----------
__global__ __launch_bounds__(1024) void kC(const float* __restrict__ W,
                                           const float* __restrict__ Y,
                                           const float* __restrict__ Wc,
                                           const float* __restrict__ bcv,
                                           float* __restrict__ out) {
  __shared__ float B[10000];      // column-major: column p at B + p*100
  __shared__ float stage[8320];   // GEMM staging; later Hf[5050]
  __shared__ float nrm[100];      // maintained squared column norms
  __shared__ float sfin[100];
  __shared__ float red[16][12];
  __shared__ int lastrot[100];    // sweep index of each column's last rotation
  __shared__ int rotflag[50];
  __shared__ int brk;

  const int b = blockIdx.x, tid = threadIdx.x;
  const int q4 = tid & 31;
  const int r32 = tid >> 5;
  const int g = tid >> 4, lane = tid & 15;  // 64 groups of 16 (wave-aligned)

  // ---- M = W^T @ Y_b  into B ----
  {
    float* Wst = stage;          // [40][104]
    float* Yst = stage + 4160;   // [40][104]
    const float* Yb = Y + (size_t)b * 40000;
    float acc[4][4];
#pragma unroll
    for (int m = 0; m < 4; ++m) acc[m][0] = acc[m][1] = acc[m][2] = acc[m][3] = 0.f;
    for (int k0 = 0; k0 < 400; k0 += 40) {
      for (int e = tid; e < 4000; e += 1024) {
        int kk = e / 100, j = e - kk * 100;
        Wst[kk * 104 + j] = W[(k0 + kk) * 100 + j];
        Yst[kk * 104 + j] = Yb[(k0 + kk) * 100 + j];
      }
      __syncthreads();
      for (int kk = 0; kk < 40; ++kk) {
        float y0 = Yst[kk * 104 + q4], y1 = Yst[kk * 104 + q4 + 32], y2 = Yst[kk * 104 + q4 + 64];
        float y3 = (q4 + 96 < 100) ? Yst[kk * 104 + q4 + 96] : 0.f;
#pragma unroll
        for (int m = 0; m < 4; ++m) {
          int p = r32 + 32 * m;
          if (p < 100) {
            float w = Wst[kk * 104 + p];
            acc[m][0] += w * y0; acc[m][1] += w * y1; acc[m][2] += w * y2; acc[m][3] += w * y3;
          }
        }
      }
      __syncthreads();
    }
#pragma unroll
    for (int m = 0; m < 4; ++m) {
      int p = r32 + 32 * m;
      if (p < 100) {
        B[p * 100 + q4] = acc[m][0];
        B[p * 100 + q4 + 32] = acc[m][1];
        B[p * 100 + q4 + 64] = acc[m][2];
        if (q4 + 96 < 100) B[p * 100 + q4 + 96] = acc[m][3];
      }
    }
  }
  if (tid < 50) rotflag[tid] = 0;
  if (tid < 100) lastrot[tid] = -1;
  __syncthreads();
  // symmetrize both triangles
  for (int e = tid; e < 5050; e += 1024) {
    int i = triu_row(e);
    int j = i + (e - ((201 * i - i * i) >> 1));
    float av = 0.5f * (B[i * 100 + j] + B[j * 100 + i]);
    B[i * 100 + j] = av;
    B[j * 100 + i] = av;
  }
  __syncthreads();
  // initial squared norms (group g covers columns g, g+64)
  for (int col = g; col < 100; col += 64) {
    const float* bp = B + col * 100;
    float4 a4 = *(const float4*)(bp + 4 * lane);
    float n = a4.x * a4.x + a4.y * a4.y + a4.z * a4.z + a4.w * a4.w;
    if (lane < 9) {
      float4 a8 = *(const float4*)(bp + 64 + 4 * lane);
      n += a8.x * a8.x + a8.y * a8.y + a8.z * a8.z + a8.w * a8.w;
    }
    n = sum16(n);
    if (lane == 0) nrm[col] = n;
  }
  __syncthreads();

  // ---- one-sided cyclic Jacobi: fused dot+rotate, DPP reduce, sweep-skip ----
  for (int r = 0; r < NRT; ++r) {
    const int rr = r % 99;
    const int sw = r / 99;
    if (g < 50) {
      int p, q;
      if (g == 0) { p = 99; q = rr; }
      else {
        p = rr + g; if (p >= 99) p -= 99;
        q = rr - g; if (q < 0) q += 99;
      }
      // skip iff both columns untouched since before the previous sweep's
      // check of this pair: d is bit-identical and was below threshold.
      if (lastrot[p] >= sw - 1 || lastrot[q] >= sw - 1) {
        float* bp = B + p * 100;
        float* bq = B + q * 100;
        float4 a4 = *(const float4*)(bp + 4 * lane);
        float4 b4 = *(const float4*)(bq + 4 * lane);
        float4 a8 = make_float4(0.f, 0.f, 0.f, 0.f), b8 = a8;
        float d = a4.x * b4.x + a4.y * b4.y + a4.z * b4.z + a4.w * b4.w;
        if (lane < 9) {
          a8 = *(const float4*)(bp + 64 + 4 * lane);
          b8 = *(const float4*)(bq + 64 + 4 * lane);
          d += a8.x * b8.x + a8.y * b8.y + a8.z * b8.z + a8.w * b8.w;
        }
        d = sum16(d);  // VALU DPP all-reduce, off the LDS pipe
        float pn = nrm[p], qn = nrm[q];
        if (d * d > SKIPTH * pn * qn + 1e-30f) {  // group-uniform branch
          float tau = (qn - pn) / (2.f * d);
          float t = copysignf(1.f, tau) / (fabsf(tau) + sqrtf(1.f + tau * tau));
          float c = 1.f / sqrtf(1.f + t * t);
          float s = t * c;
          float4 n4, m4;
          n4.x = c * a4.x - s * b4.x; n4.y = c * a4.y - s * b4.y;
          n4.z = c * a4.z - s * b4.z; n4.w = c * a4.w - s * b4.w;
          m4.x = s * a4.x + c * b4.x; m4.y = s * a4.y + c * b4.y;
          m4.z = s * a4.z + c * b4.z; m4.w = s * a4.w + c * b4.w;
          *(float4*)(bp + 4 * lane) = n4;
          *(float4*)(bq + 4 * lane) = m4;
          if (lane < 9) {
            n4.x = c * a8.x - s * b8.x; n4.y = c * a8.y - s * b8.y;
            n4.z = c * a8.z - s * b8.z; n4.w = c * a8.w - s * b8.w;
            m4.x = s * a8.x + c * b8.x; m4.y = s * a8.y + c * b8.y;
            m4.z = s * a8.z + c * b8.z; m4.w = s * a8.w + c * b8.w;
            *(float4*)(bp + 64 + 4 * lane) = n4;
            *(float4*)(bq + 64 + 4 * lane) = m4;
          }
          if (lane == 0) {
            nrm[p] = pn - t * d;   // exact Jacobi diagonal update
            nrm[q] = qn + t * d;
            lastrot[p] = sw;
            lastrot[q] = sw;
            rotflag[g] = 1;        // sticky, no atomic
          }
        }
      }
    }
    __syncthreads();
    if (rr == 98) {  // sweep end: OR the sticky flags, clear, maybe break
      if (tid < 64) {
        int v = (tid < 50) ? rotflag[tid] : 0;
#pragma unroll
        for (int off = 32; off > 0; off >>= 1) v += __shfl_xor(v, off);
        if (tid == 0) brk = (v == 0) ? 1 : 0;
        if (tid < 50) rotflag[tid] = 0;
      }
      __syncthreads();
      if (brk) break;
    }
  }

  // ---- exact final scales: sfin[p] = log(max(||b_p||,EPSV)) / ||b_p||^2 ----
  for (int col = g; col < 100; col += 64) {
    const float* bp = B + col * 100;
    float4 a4 = *(const float4*)(bp + 4 * lane);
    float n = a4.x * a4.x + a4.y * a4.y + a4.z * a4.z + a4.w * a4.w;
    if (lane < 9) {
      float4 a8 = *(const float4*)(bp + 64 + 4 * lane);
      n += a8.x * a8.x + a8.y * a8.y + a8.z * a8.z + a8.w * a8.w;
    }
    n = sum16(n);
    if (lane == 0) sfin[col] = logf(fmaxf(sqrtf(n), EPSV)) / n;
  }
  __syncthreads();

  // ---- Hf (triu flat) = sum_p sfin[p] * b_p b_p^T ----
  float* Hf = stage;
  {
    float hacc[4][4];
#pragma unroll
    for (int m = 0; m < 4; ++m) hacc[m][0] = hacc[m][1] = hacc[m][2] = hacc[m][3] = 0.f;
    for (int p = 0; p < 100; ++p) {
      float l = sfin[p];
      const float* vr = B + p * 100;
      float vj0 = vr[q4], vj1 = vr[q4 + 32], vj2 = vr[q4 + 64];
      float vj3 = (q4 + 96 < 100) ? vr[q4 + 96] : 0.f;
#pragma unroll
      for (int m = 0; m < 4; ++m) {
        int i = r32 + 32 * m;
        if (i < 100) {
          float vil = vr[i] * l;
          hacc[m][0] += vil * vj0; hacc[m][1] += vil * vj1;
          hacc[m][2] += vil * vj2; hacc[m][3] += vil * vj3;
        }
      }
    }
    __syncthreads();
#pragma unroll
    for (int m = 0; m < 4; ++m) {
      int i = r32 + 32 * m;
      if (i >= 100) continue;
#pragma unroll
      for (int n = 0; n < 4; ++n) {
        int j = q4 + 32 * n;
        if (j < 100 && i <= j) Hf[((201 * i - i * i) >> 1) + (j - i)] = hacc[m][n];
      }
    }
  }
  __syncthreads();

  // ---- classifier ----
  float accc[10];
#pragma unroll
  for (int c = 0; c < 10; ++c) accc[c] = 0.f;
  for (int e = tid; e < 5050; e += 1024) {
    float h = Hf[e];
#pragma unroll
    for (int c = 0; c < 10; ++c) accc[c] += h * Wc[c * 5050 + e];
  }
  const int lane64 = tid & 63, wv = tid >> 6;
#pragma unroll
  for (int c = 0; c < 10; ++c) {
    float v = accc[c];
#pragma unroll
    for (int off = 32; off > 0; off >>= 1) v += __shfl_down(v, off);
    if (lane64 == 0) red[wv][c] = v;
  }
  __syncthreads();
  if (tid < 10) {
    float s = bcv[tid];
#pragma unroll
    for (int w = 0; w < 16; ++w) s += red[w][tid];
    out[b * 10 + tid] = s;
  }
}

extern "C" void kernel_launch(void* const* d_in, const int* in_sizes, int n_in,
                              void* d_out, int out_size, void* d_ws, size_t ws_size,
                              hipStream_t stream) {
  const float* x = (const float*)d_in[0];
  const float* W1 = (const float*)d_in[1];
  const float* W2 = (const float*)d_in[2];
  const float* Wc = (const float*)d_in[3];
  const float* bc = (const float*)d_in[4];
  float* out = (float*)d_out;

  float* W = (float*)d_ws;        // 400*100 floats
  float* Y = W + 40000;           // 256*400*100 floats (~41 MB)

  kA<<<157, 256, 0, stream>>>(W1, W2, W);
  kB<<<dim3(25, 256), 256, 0, stream>>>(x, W, Y);
  kC<<<256, 1024, 0, stream>>>(W, Y, Wc, bc, out);
}

// Round 11
// 1288.309 us; speedup vs baseline: 1.5375x; 1.0676x over previous
//
#include <hip/hip_runtime.h>
#include <math.h>

#define EPSV 1e-4f
#define NSWEEP 10
#define NRT (99 * NSWEEP)
#define SKIPTH 1e-9f
#define PIT 132          // column pitch in floats: 528B, 16B-aligned, ==4 mod 32 banks

// ---------- 16-lane all-reduce sum on the VALU (DPP), no LDS pipe ----------
template <int CTRL>
__device__ __forceinline__ float dppadd(float x) {
  int y = __builtin_amdgcn_update_dpp(0, __float_as_int(x), CTRL, 0xF, 0xF, false);
  return x + __int_as_float(y);
}
__device__ __forceinline__ float sum16(float x) {
  x = dppadd<0xB1>(x);   // quad_perm [1,0,3,2]  == xor 1
  x = dppadd<0x4E>(x);   // quad_perm [2,3,0,1]  == xor 2
  x = dppadd<0x124>(x);  // row_ror:4
  x = dppadd<0x128>(x);  // row_ror:8
  return x;
}

// ---------- Kernel A: W = W1 @ W2 (400x200 @ 200x100 -> 400x100) ----------
__global__ __launch_bounds__(256) void kA(const float* __restrict__ W1,
                                          const float* __restrict__ W2,
                                          float* __restrict__ W) {
  int e = blockIdx.x * 256 + threadIdx.x;
  if (e >= 400 * 100) return;
  int i = e / 100, j = e - (e / 100) * 100;
  float s = 0.f;
#pragma unroll 4
  for (int k = 0; k < 200; ++k) s += W1[i * 200 + k] * W2[k * 100 + j];
  W[e] = s;
}

// ---------- Kernel B: Y[b] = x[b] @ W  (400x400 @ 400x100) ----------
__global__ __launch_bounds__(256) void kB(const float* __restrict__ x,
                                          const float* __restrict__ W,
                                          float* __restrict__ Y) {
  __shared__ float xs[16][41];
  __shared__ float ws[40][104];
  const int b = blockIdx.y, rt = blockIdx.x;
  const int tid = threadIdx.x;
  const int tc = tid & 31, tr = tid >> 5;
  const float* xb = x + (size_t)b * 160000 + (size_t)rt * 16 * 400;
  float acc[2][4] = {{0.f, 0.f, 0.f, 0.f}, {0.f, 0.f, 0.f, 0.f}};
  for (int k0 = 0; k0 < 400; k0 += 40) {
    for (int e = tid; e < 640; e += 256) {
      int r = e / 40, kk = e - r * 40;
      xs[r][kk] = xb[r * 400 + k0 + kk];
    }
    for (int e = tid; e < 4000; e += 256) {
      int kk = e / 100, j = e - kk * 100;
      ws[kk][j] = W[(k0 + kk) * 100 + j];
    }
    __syncthreads();
#pragma unroll 8
    for (int kk = 0; kk < 40; ++kk) {
      float a0 = xs[tr][kk], a1 = xs[tr + 8][kk];
      float b0 = ws[kk][tc], b1 = ws[kk][tc + 32], b2 = ws[kk][tc + 64];
      float b3 = (tc + 96 < 100) ? ws[kk][tc + 96] : 0.f;
      acc[0][0] += a0 * b0; acc[0][1] += a0 * b1; acc[0][2] += a0 * b2; acc[0][3] += a0 * b3;
      acc[1][0] += a1 * b0; acc[1][1] += a1 * b1; acc[1][2] += a1 * b2; acc[1][3] += a1 * b3;
    }
    __syncthreads();
  }
  float* Yb = Y + (size_t)b * 40000 + (size_t)rt * 1600;
#pragma unroll
  for (int rr = 0; rr < 2; ++rr) {
    int r = tr + 8 * rr;
#pragma unroll
    for (int u = 0; u < 4; ++u) {
      int c = tc + 32 * u;
      if (c < 100) Yb[r * 100 + c] = acc[rr][u];
    }
  }
}

// flat triu index (n=100) -> row (one-off use in symmetrize)
__device__ __forceinline__ int triu_row(int e) {
  int i = (int)((201.0f - sqrtf(40401.0f - 8.0f * (float)e)) * 0.5f);
  if (i < 0) i = 0;
  if (i > 99) i = 99;
  while (i > 0 && (201 * i - i * i) > 2 * e) --i;
  while ((201 * (i + 1) - (i + 1) * (i + 1)) <= 2 * e) ++i;
  return i;
}

// ---------- Kernel C: M = W^T Y_b ; logm via ONE-SIDED Jacobi ; classifier ----------
__global__ __launch_bounds__(1024) void kC(const float* __restrict__ W,
                                           const float* __restrict__ Y,
                                           const float* __restrict__ Wc,
                                           const float* __restrict__ bcv,
                                           float* __restrict__ out) {
  __shared__ float B[100 * PIT];  // column-major, pitch PIT; rows 100..127 zero pad
  __shared__ float stage[8320];   // GEMM staging; later Hf[5050]
  __shared__ float nrm[100];      // maintained squared column norms
  __shared__ float sfin[100];
  __shared__ float red[16][12];
  __shared__ float tstat[50];
  __shared__ int rotflag[50];
  __shared__ int brk;

  const int b = blockIdx.x, tid = threadIdx.x;
  const int q4 = tid & 31;
  const int r32 = tid >> 5;
  const int g = tid >> 4, lane = tid & 15;  // 64 groups of 16 (wave-aligned)
  const int o0 = 4 * lane;                  // float offsets within a column
  // (second half at o0 + 64 -> folds to ds offset:256)

  // ---- M = W^T @ Y_b  into B ----
  {
    float* Wst = stage;          // [40][104]
    float* Yst = stage + 4160;   // [40][104]
    const float* Yb = Y + (size_t)b * 40000;
    float acc[4][4];
#pragma unroll
    for (int m = 0; m < 4; ++m) acc[m][0] = acc[m][1] = acc[m][2] = acc[m][3] = 0.f;
    for (int k0 = 0; k0 < 400; k0 += 40) {
      for (int e = tid; e < 4000; e += 1024) {
        int kk = e / 100, j = e - kk * 100;
        Wst[kk * 104 + j] = W[(k0 + kk) * 100 + j];
        Yst[kk * 104 + j] = Yb[(k0 + kk) * 100 + j];
      }
      __syncthreads();
      for (int kk = 0; kk < 40; ++kk) {
        float y0 = Yst[kk * 104 + q4], y1 = Yst[kk * 104 + q4 + 32], y2 = Yst[kk * 104 + q4 + 64];
        float y3 = (q4 + 96 < 100) ? Yst[kk * 104 + q4 + 96] : 0.f;
#pragma unroll
        for (int m = 0; m < 4; ++m) {
          int p = r32 + 32 * m;
          if (p < 100) {
            float w = Wst[kk * 104 + p];
            acc[m][0] += w * y0; acc[m][1] += w * y1; acc[m][2] += w * y2; acc[m][3] += w * y3;
          }
        }
      }
      __syncthreads();
    }
#pragma unroll
    for (int m = 0; m < 4; ++m) {
      int p = r32 + 32 * m;
      if (p < 100) {
        B[p * PIT + q4] = acc[m][0];
        B[p * PIT + q4 + 32] = acc[m][1];
        B[p * PIT + q4 + 64] = acc[m][2];
        if (q4 + 96 < 100) B[p * PIT + q4 + 96] = acc[m][3];
      }
    }
  }
  if (tid < 50) { rotflag[tid] = 0; tstat[tid] = 0.f; }
  // zero the pad rows [100,132) of every column
  for (int e = tid; e < 3200; e += 1024) {
    int col = e >> 5, row = 100 + (e & 31);
    B[col * PIT + row] = 0.f;
  }
  __syncthreads();
  // symmetrize both triangles
  for (int e = tid; e < 5050; e += 1024) {
    int i = triu_row(e);
    int j = i + (e - ((201 * i - i * i) >> 1));
    float av = 0.5f * (B[i * PIT + j] + B[j * PIT + i]);
    B[i * PIT + j] = av;
    B[j * PIT + i] = av;
  }
  __syncthreads();
  // initial squared norms (group g covers columns g, g+64) — uniform 2-load
  for (int col = g; col < 100; col += 64) {
    const float* bp = B + col * PIT;
    float4 a0 = *(const float4*)(bp + o0);
    float4 a1 = *(const float4*)(bp + o0 + 64);
    float n = a0.x * a0.x + a0.y * a0.y + a0.z * a0.z + a0.w * a0.w
            + a1.x * a1.x + a1.y * a1.y + a1.z * a1.z + a1.w * a1.w;
    n = sum16(n);
    if (lane == 0) nrm[col] = n;
  }
  __syncthreads();

  // ---- one-sided cyclic Jacobi: fused dot+rotate, incremental schedule ----
  // round rr: g==0 -> (99, rr); g>0 -> ((rr+g)%99, (rr-g+99)%99)
  int p, q;
  if (g == 0) { p = 99; q = 0; }
  else { p = g; q = 99 - g; }
  int pp = p * PIT, qq = q * PIT;
  float tacc = 0.f;
  int any = 0;

  for (int r = 0; r < NRT; ++r) {
    const int rr = r % 99;
    if (g < 50) {
      float* bp = B + pp;
      float* bq = B + qq;
      float4 a0 = *(const float4*)(bp + o0);
      float4 a1 = *(const float4*)(bp + o0 + 64);
      float4 b0 = *(const float4*)(bq + o0);
      float4 b1 = *(const float4*)(bq + o0 + 64);
      float d = a0.x * b0.x + a0.y * b0.y + a0.z * b0.z + a0.w * b0.w
              + a1.x * b1.x + a1.y * b1.y + a1.z * b1.z + a1.w * b1.w;
      d = sum16(d);  // VALU DPP all-reduce
      float pn = nrm[p], qn = nrm[q];
      if (d * d > SKIPTH * pn * qn + 1e-30f) {  // group-uniform branch
        float tau = (qn - pn) / (2.f * d);
        float t = copysignf(1.f, tau) / (fabsf(tau) + sqrtf(1.f + tau * tau));
        float c = 1.f / sqrtf(1.f + t * t);
        float s = t * c;
        float4 n4, m4;
        n4.x = c * a0.x - s * b0.x; n4.y = c * a0.y - s * b0.y;
        n4.z = c * a0.z - s * b0.z; n4.w = c * a0.w - s * b0.w;
        m4.x = s * a0.x + c * b0.x; m4.y = s * a0.y + c * b0.y;
        m4.z = s * a0.z + c * b0.z; m4.w = s * a0.w + c * b0.w;
        *(float4*)(bp + o0) = n4;
        *(float4*)(bq + o0) = m4;
        n4.x = c * a1.x - s * b1.x; n4.y = c * a1.y - s * b1.y;
        n4.z = c * a1.z - s * b1.z; n4.w = c * a1.w - s * b1.w;
        m4.x = s * a1.x + c * b1.x; m4.y = s * a1.y + c * b1.y;
        m4.z = s * a1.z + c * b1.z; m4.w = s * a1.w + c * b1.w;
        *(float4*)(bp + o0 + 64) = n4;
        *(float4*)(bq + o0 + 64) = m4;
        tacc += t * t;
        any = 1;
        if (lane == 0) {
          nrm[p] = pn - t * d;   // exact Jacobi diagonal update
          nrm[q] = qn + t * d;
        }
      }
    }
    __syncthreads();
    // advance schedule incrementally (matches rr+1)
    ++q; qq += PIT; if (q == 99) { q = 0; qq = 0; }
    if (g != 0) { ++p; pp += PIT; if (p == 99) { p = 0; pp = 0; } }
    if (rr == 98) {  // sweep end: reduce rot flags + sum of t^2
      if (g < 50 && lane == 0) { rotflag[g] = any; tstat[g] = tacc; }
      any = 0; tacc = 0.f;
      __syncthreads();
      if (tid < 64) {
        int v = (tid < 50) ? rotflag[tid] : 0;
        float tv = (tid < 50) ? tstat[tid] : 0.f;
#pragma unroll
        for (int off = 32; off > 0; off >>= 1) {
          v += __shfl_xor(v, off);
          tv += __shfl_xor(tv, off);
        }
        if (tid == 0) brk = (v == 0 || tv < 1e-6f) ? 1 : 0;
      }
      __syncthreads();
      if (brk) break;
    }
  }

  // ---- exact final scales: sfin[p] = log(max(||b_p||,EPSV)) / ||b_p||^2 ----
  for (int col = g; col < 100; col += 64) {
    const float* bp = B + col * PIT;
    float4 a0 = *(const float4*)(bp + o0);
    float4 a1 = *(const float4*)(bp + o0 + 64);
    float n = a0.x * a0.x + a0.y * a0.y + a0.z * a0.z + a0.w * a0.w
            + a1.x * a1.x + a1.y * a1.y + a1.z * a1.z + a1.w * a1.w;
    n = sum16(n);
    if (lane == 0) sfin[col] = logf(fmaxf(sqrtf(n), EPSV)) / n;
  }
  __syncthreads();

  // ---- Hf (triu flat) = sum_p sfin[p] * b_p b_p^T ----
  float* Hf = stage;
  {
    float hacc[4][4];
#pragma unroll
    for (int m = 0; m < 4; ++m) hacc[m][0] = hacc[m][1] = hacc[m][2] = hacc[m][3] = 0.f;
    for (int pc = 0; pc < 100; ++pc) {
      float l = sfin[pc];
      const float* vr = B + pc * PIT;
      float vj0 = vr[q4], vj1 = vr[q4 + 32], vj2 = vr[q4 + 64];
      float vj3 = (q4 + 96 < 100) ? vr[q4 + 96] : 0.f;
#pragma unroll
      for (int m = 0; m < 4; ++m) {
        int i = r32 + 32 * m;
        if (i < 100) {
          float vil = vr[i] * l;
          hacc[m][0] += vil * vj0; hacc[m][1] += vil * vj1;
          hacc[m][2] += vil * vj2; hacc[m][3] += vil * vj3;
        }
      }
    }
    __syncthreads();
#pragma unroll
    for (int m = 0; m < 4; ++m) {
      int i = r32 + 32 * m;
      if (i >= 100) continue;
#pragma unroll
      for (int n = 0; n < 4; ++n) {
        int j = q4 + 32 * n;
        if (j < 100 && i <= j) Hf[((201 * i - i * i) >> 1) + (j - i)] = hacc[m][n];
      }
    }
  }
  __syncthreads();

  // ---- classifier ----
  float accc[10];
#pragma unroll
  for (int c = 0; c < 10; ++c) accc[c] = 0.f;
  for (int e = tid; e < 5050; e += 1024) {
    float h = Hf[e];
#pragma unroll
    for (int c = 0; c < 10; ++c) accc[c] += h * Wc[c * 5050 + e];
  }
  const int lane64 = tid & 63, wv = tid >> 6;
#pragma unroll
  for (int c = 0; c < 10; ++c) {
    float v = accc[c];
#pragma unroll
    for (int off = 32; off > 0; off >>= 1) v += __shfl_down(v, off);
    if (lane64 == 0) red[wv][c] = v;
  }
  __syncthreads();
  if (tid < 10) {
    float s = bcv[tid];
#pragma unroll
    for (int w = 0; w < 16; ++w) s += red[w][tid];
    out[b * 10 + tid] = s;
  }
}

extern "C" void kernel_launch(void* const* d_in, const int* in_sizes, int n_in,
                              void* d_out, int out_size, void* d_ws, size_t ws_size,
                              hipStream_t stream) {
  const float* x = (const float*)d_in[0];
  const float* W1 = (const float*)d_in[1];
  const float* W2 = (const float*)d_in[2];
  const float* Wc = (const float*)d_in[3];
  const float* bc = (const float*)d_in[4];
  float* out = (float*)d_out;

  float* W = (float*)d_ws;        // 400*100 floats
  float* Y = W + 40000;           // 256*400*100 floats (~41 MB)

  kA<<<157, 256, 0, stream>>>(W1, W2, W);
  kB<<<dim3(25, 256), 256, 0, stream>>>(x, W, Y);
  kC<<<256, 1024, 0, stream>>>(W, Y, Wc, bc, out);
}

// Round 12
// 1246.830 us; speedup vs baseline: 1.5886x; 1.0333x over previous
//
#include <hip/hip_runtime.h>
#include <math.h>

#define EPSV 1e-4f
#define NSWEEP 10
#define NRT (99 * NSWEEP)
#define SKIPTH 1e-8f
#define TAUBRK 1e-3f

// ---------- 16-lane all-reduce sum on the VALU (DPP), no LDS pipe ----------
template <int CTRL>
__device__ __forceinline__ float dppadd(float x) {
  int y = __builtin_amdgcn_update_dpp(0, __float_as_int(x), CTRL, 0xF, 0xF, false);
  return x + __int_as_float(y);
}
__device__ __forceinline__ float sum16(float x) {
  x = dppadd<0xB1>(x);   // quad_perm [1,0,3,2]  == xor 1
  x = dppadd<0x4E>(x);   // quad_perm [2,3,0,1]  == xor 2
  x = dppadd<0x124>(x);  // row_ror:4
  x = dppadd<0x128>(x);  // row_ror:8
  return x;
}

// ---------- Kernel A: W = W1 @ W2 (400x200 @ 200x100 -> 400x100) ----------
__global__ __launch_bounds__(256) void kA(const float* __restrict__ W1,
                                          const float* __restrict__ W2,
                                          float* __restrict__ W) {
  int e = blockIdx.x * 256 + threadIdx.x;
  if (e >= 400 * 100) return;
  int i = e / 100, j = e - (e / 100) * 100;
  float s = 0.f;
#pragma unroll 4
  for (int k = 0; k < 200; ++k) s += W1[i * 200 + k] * W2[k * 100 + j];
  W[e] = s;
}

// ---------- Kernel B: Y[b] = x[b] @ W  (400x400 @ 400x100) ----------
__global__ __launch_bounds__(256) void kB(const float* __restrict__ x,
                                          const float* __restrict__ W,
                                          float* __restrict__ Y) {
  __shared__ float xs[16][41];
  __shared__ float ws[40][104];
  const int b = blockIdx.y, rt = blockIdx.x;
  const int tid = threadIdx.x;
  const int tc = tid & 31, tr = tid >> 5;
  const float* xb = x + (size_t)b * 160000 + (size_t)rt * 16 * 400;
  float acc[2][4] = {{0.f, 0.f, 0.f, 0.f}, {0.f, 0.f, 0.f, 0.f}};
  for (int k0 = 0; k0 < 400; k0 += 40) {
    for (int e = tid; e < 640; e += 256) {
      int r = e / 40, kk = e - r * 40;
      xs[r][kk] = xb[r * 400 + k0 + kk];
    }
    for (int e = tid; e < 4000; e += 256) {
      int kk = e / 100, j = e - kk * 100;
      ws[kk][j] = W[(k0 + kk) * 100 + j];
    }
    __syncthreads();
#pragma unroll 8
    for (int kk = 0; kk < 40; ++kk) {
      float a0 = xs[tr][kk], a1 = xs[tr + 8][kk];
      float b0 = ws[kk][tc], b1 = ws[kk][tc + 32], b2 = ws[kk][tc + 64];
      float b3 = (tc + 96 < 100) ? ws[kk][tc + 96] : 0.f;
      acc[0][0] += a0 * b0; acc[0][1] += a0 * b1; acc[0][2] += a0 * b2; acc[0][3] += a0 * b3;
      acc[1][0] += a1 * b0; acc[1][1] += a1 * b1; acc[1][2] += a1 * b2; acc[1][3] += a1 * b3;
    }
    __syncthreads();
  }
  float* Yb = Y + (size_t)b * 40000 + (size_t)rt * 1600;
#pragma unroll
  for (int rr = 0; rr < 2; ++rr) {
    int r = tr + 8 * rr;
#pragma unroll
    for (int u = 0; u < 4; ++u) {
      int c = tc + 32 * u;
      if (c < 100) Yb[r * 100 + c] = acc[rr][u];
    }
  }
}

// flat triu index (n=100) -> row (one-off use in symmetrize)
__device__ __forceinline__ int triu_row(int e) {
  int i = (int)((201.0f - sqrtf(40401.0f - 8.0f * (float)e)) * 0.5f);
  if (i < 0) i = 0;
  if (i > 99) i = 99;
  while (i > 0 && (201 * i - i * i) > 2 * e) --i;
  while ((201 * (i + 1) - (i + 1) * (i + 1)) <= 2 * e) ++i;
  return i;
}

// ---------- Kernel C: M = W^T Y_b ; logm via ONE-SIDED Jacobi ; classifier ----------
__global__ __launch_bounds__(1024) void kC(const float* __restrict__ W,
                                           const float* __restrict__ Y,
                                           const float* __restrict__ Wc,
                                           const float* __restrict__ bcv,
                                           float* __restrict__ out) {
  __shared__ float B[10000];      // column-major: column p at B + p*100
  __shared__ float stage[8320];   // GEMM staging; later Hf[5050]
  __shared__ float nrm[100];      // maintained squared column norms
  __shared__ float sfin[100];
  __shared__ float red[16][12];
  __shared__ float tstat[50];
  __shared__ int rotflag[50];
  __shared__ int brk;

  const int b = blockIdx.x, tid = threadIdx.x;
  const int q4 = tid & 31;
  const int r32 = tid >> 5;
  const int g = tid >> 4, lane = tid & 15;  // 64 groups of 16 (wave-aligned)

  // ---- M = W^T @ Y_b  into B ----
  {
    float* Wst = stage;          // [40][104]
    float* Yst = stage + 4160;   // [40][104]
    const float* Yb = Y + (size_t)b * 40000;
    float acc[4][4];
#pragma unroll
    for (int m = 0; m < 4; ++m) acc[m][0] = acc[m][1] = acc[m][2] = acc[m][3] = 0.f;
    for (int k0 = 0; k0 < 400; k0 += 40) {
      for (int e = tid; e < 4000; e += 1024) {
        int kk = e / 100, j = e - kk * 100;
        Wst[kk * 104 + j] = W[(k0 + kk) * 100 + j];
        Yst[kk * 104 + j] = Yb[(k0 + kk) * 100 + j];
      }
      __syncthreads();
      for (int kk = 0; kk < 40; ++kk) {
        float y0 = Yst[kk * 104 + q4], y1 = Yst[kk * 104 + q4 + 32], y2 = Yst[kk * 104 + q4 + 64];
        float y3 = (q4 + 96 < 100) ? Yst[kk * 104 + q4 + 96] : 0.f;
#pragma unroll
        for (int m = 0; m < 4; ++m) {
          int p = r32 + 32 * m;
          if (p < 100) {
            float w = Wst[kk * 104 + p];
            acc[m][0] += w * y0; acc[m][1] += w * y1; acc[m][2] += w * y2; acc[m][3] += w * y3;
          }
        }
      }
      __syncthreads();
    }
#pragma unroll
    for (int m = 0; m < 4; ++m) {
      int p = r32 + 32 * m;
      if (p < 100) {
        B[p * 100 + q4] = acc[m][0];
        B[p * 100 + q4 + 32] = acc[m][1];
        B[p * 100 + q4 + 64] = acc[m][2];
        if (q4 + 96 < 100) B[p * 100 + q4 + 96] = acc[m][3];
      }
    }
  }
  if (tid < 50) { rotflag[tid] = 0; tstat[tid] = 0.f; }
  __syncthreads();
  // symmetrize both triangles
  for (int e = tid; e < 5050; e += 1024) {
    int i = triu_row(e);
    int j = i + (e - ((201 * i - i * i) >> 1));
    float av = 0.5f * (B[i * 100 + j] + B[j * 100 + i]);
    B[i * 100 + j] = av;
    B[j * 100 + i] = av;
  }
  __syncthreads();
  // initial squared norms (group g covers columns g, g+64)
  for (int col = g; col < 100; col += 64) {
    const float* bp = B + col * 100;
    float4 a4 = *(const float4*)(bp + 4 * lane);
    float n = a4.x * a4.x + a4.y * a4.y + a4.z * a4.z + a4.w * a4.w;
    if (lane < 9) {
      float4 a8 = *(const float4*)(bp + 64 + 4 * lane);
      n += a8.x * a8.x + a8.y * a8.y + a8.z * a8.z + a8.w * a8.w;
    }
    n = sum16(n);
    if (lane == 0) nrm[col] = n;
  }
  __syncthreads();

  // ---- one-sided cyclic Jacobi: fused dot+rotate, incremental schedule ----
  int p, q;
  if (g == 0) { p = 99; q = 0; }
  else { p = g; q = 99 - g; }
  int pp = p * 100, qq = q * 100;
  float tacc = 0.f;
  int any = 0;

  for (int r = 0; r < NRT; ++r) {
    const int rr = r % 99;
    if (g < 50) {
      float* bp = B + pp;
      float* bq = B + qq;
      float4 a4 = *(const float4*)(bp + 4 * lane);
      float4 b4 = *(const float4*)(bq + 4 * lane);
      float4 a8 = make_float4(0.f, 0.f, 0.f, 0.f), b8 = a8;
      float d = a4.x * b4.x + a4.y * b4.y + a4.z * b4.z + a4.w * b4.w;
      if (lane < 9) {
        a8 = *(const float4*)(bp + 64 + 4 * lane);
        b8 = *(const float4*)(bq + 64 + 4 * lane);
        d += a8.x * b8.x + a8.y * b8.y + a8.z * b8.z + a8.w * b8.w;
      }
      d = sum16(d);  // VALU DPP all-reduce
      float pn = nrm[p], qn = nrm[q];
      if (d * d > SKIPTH * pn * qn + 1e-30f) {  // group-uniform branch
        float tau = (qn - pn) / (2.f * d);
        float t = copysignf(1.f, tau) / (fabsf(tau) + sqrtf(1.f + tau * tau));
        float c = 1.f / sqrtf(1.f + t * t);
        float s = t * c;
        float4 n4, m4;
        n4.x = c * a4.x - s * b4.x; n4.y = c * a4.y - s * b4.y;
        n4.z = c * a4.z - s * b4.z; n4.w = c * a4.w - s * b4.w;
        m4.x = s * a4.x + c * b4.x; m4.y = s * a4.y + c * b4.y;
        m4.z = s * a4.z + c * b4.z; m4.w = s * a4.w + c * b4.w;
        *(float4*)(bp + 4 * lane) = n4;
        *(float4*)(bq + 4 * lane) = m4;
        if (lane < 9) {
          n4.x = c * a8.x - s * b8.x; n4.y = c * a8.y - s * b8.y;
          n4.z = c * a8.z - s * b8.z; n4.w = c * a8.w - s * b8.w;
          m4.x = s * a8.x + c * b8.x; m4.y = s * a8.y + c * b8.y;
          m4.z = s * a8.z + c * b8.z; m4.w = s * a8.w + c * b8.w;
          *(float4*)(bp + 64 + 4 * lane) = n4;
          *(float4*)(bq + 64 + 4 * lane) = m4;
        }
        tacc += t * t;
        any = 1;
        if (lane == 0) {
          nrm[p] = pn - t * d;   // exact Jacobi diagonal update
          nrm[q] = qn + t * d;
        }
      }
    }
    __syncthreads();
    // advance schedule incrementally (matches rr+1)
    ++q; qq += 100; if (q == 99) { q = 0; qq = 0; }
    if (g != 0) { ++p; pp += 100; if (p == 99) { p = 0; pp = 0; } }
    if (rr == 98) {  // sweep end: reduce rot flags + sum of t^2
      if (g < 50 && lane == 0) { rotflag[g] = any; tstat[g] = tacc; }
      any = 0; tacc = 0.f;
      __syncthreads();
      if (tid < 64) {
        int v = (tid < 50) ? rotflag[tid] : 0;
        float tv = (tid < 50) ? tstat[tid] : 0.f;
#pragma unroll
        for (int off = 32; off > 0; off >>= 1) {
          v += __shfl_xor(v, off);
          tv += __shfl_xor(tv, off);
        }
        if (tid == 0) brk = (v == 0 || tv < TAUBRK) ? 1 : 0;
      }
      __syncthreads();
      if (brk) break;
    }
  }

  // ---- exact final scales: sfin[p] = log(max(||b_p||,EPSV)) / ||b_p||^2 ----
  for (int col = g; col < 100; col += 64) {
    const float* bp = B + col * 100;
    float4 a4 = *(const float4*)(bp + 4 * lane);
    float n = a4.x * a4.x + a4.y * a4.y + a4.z * a4.z + a4.w * a4.w;
    if (lane < 9) {
      float4 a8 = *(const float4*)(bp + 64 + 4 * lane);
      n += a8.x * a8.x + a8.y * a8.y + a8.z * a8.z + a8.w * a8.w;
    }
    n = sum16(n);
    if (lane == 0) sfin[col] = logf(fmaxf(sqrtf(n), EPSV)) / n;
  }
  __syncthreads();

  // ---- Hf (triu flat) = sum_p sfin[p] * b_p b_p^T ----
  float* Hf = stage;
  {
    float hacc[4][4];
#pragma unroll
    for (int m = 0; m < 4; ++m) hacc[m][0] = hacc[m][1] = hacc[m][2] = hacc[m][3] = 0.f;
    for (int pc = 0; pc < 100; ++pc) {
      float l = sfin[pc];
      const float* vr = B + pc * 100;
      float vj0 = vr[q4], vj1 = vr[q4 + 32], vj2 = vr[q4 + 64];
      float vj3 = (q4 + 96 < 100) ? vr[q4 + 96] : 0.f;
#pragma unroll
      for (int m = 0; m < 4; ++m) {
        int i = r32 + 32 * m;
        if (i < 100) {
          float vil = vr[i] * l;
          hacc[m][0] += vil * vj0; hacc[m][1] += vil * vj1;
          hacc[m][2] += vil * vj2; hacc[m][3] += vil * vj3;
        }
      }
    }
    __syncthreads();
#pragma unroll
    for (int m = 0; m < 4; ++m) {
      int i = r32 + 32 * m;
      if (i >= 100) continue;
#pragma unroll
      for (int n = 0; n < 4; ++n) {
        int j = q4 + 32 * n;
        if (j < 100 && i <= j) Hf[((201 * i - i * i) >> 1) + (j - i)] = hacc[m][n];
      }
    }
  }
  __syncthreads();

  // ---- classifier ----
  float accc[10];
#pragma unroll
  for (int c = 0; c < 10; ++c) accc[c] = 0.f;
  for (int e = tid; e < 5050; e += 1024) {
    float h = Hf[e];
#pragma unroll
    for (int c = 0; c < 10; ++c) accc[c] += h * Wc[c * 5050 + e];
  }
  const int lane64 = tid & 63, wv = tid >> 6;
#pragma unroll
  for (int c = 0; c < 10; ++c) {
    float v = accc[c];
#pragma unroll
    for (int off = 32; off > 0; off >>= 1) v += __shfl_down(v, off);
    if (lane64 == 0) red[wv][c] = v;
  }
  __syncthreads();
  if (tid < 10) {
    float s = bcv[tid];
#pragma unroll
    for (int w = 0; w < 16; ++w) s += red[w][tid];
    out[b * 10 + tid] = s;
  }
}

extern "C" void kernel_launch(void* const* d_in, const int* in_sizes, int n_in,
                              void* d_out, int out_size, void* d_ws, size_t ws_size,
                              hipStream_t stream) {
  const float* x = (const float*)d_in[0];
  const float* W1 = (const float*)d_in[1];
  const float* W2 = (const float*)d_in[2];
  const float* Wc = (const float*)d_in[3];
  const float* bc = (const float*)d_in[4];
  float* out = (float*)d_out;

  float* W = (float*)d_ws;        // 400*100 floats
  float* Y = W + 40000;           // 256*400*100 floats (~41 MB)

  kA<<<157, 256, 0, stream>>>(W1, W2, W);
  kB<<<dim3(25, 256), 256, 0, stream>>>(x, W, Y);
  kC<<<256, 1024, 0, stream>>>(W, Y, Wc, bc, out);
}

// Round 14
// 1217.486 us; speedup vs baseline: 1.6269x; 1.0241x over previous
//
#include <hip/hip_runtime.h>
#include <math.h>

#define EPSV 1e-4f
#define NSWEEP 10
#define NRT (99 * NSWEEP)
#define SKIPTH 1e-8f
#define TAUBRK 1e-3f

// ---------- 16-lane all-reduce sum on the VALU (DPP), no LDS pipe ----------
template <int CTRL>
__device__ __forceinline__ float dppadd(float x) {
  int y = __builtin_amdgcn_update_dpp(0, __float_as_int(x), CTRL, 0xF, 0xF, false);
  return x + __int_as_float(y);
}
__device__ __forceinline__ float sum16(float x) {
  x = dppadd<0xB1>(x);   // quad_perm [1,0,3,2]  == xor 1
  x = dppadd<0x4E>(x);   // quad_perm [2,3,0,1]  == xor 2
  x = dppadd<0x124>(x);  // row_ror:4
  x = dppadd<0x128>(x);  // row_ror:8
  return x;
}

// ---------- Kernel A: W = W1 @ W2 (400x200 @ 200x100 -> 400x100) ----------
__global__ __launch_bounds__(256) void kA(const float* __restrict__ W1,
                                          const float* __restrict__ W2,
                                          float* __restrict__ W) {
  int e = blockIdx.x * 256 + threadIdx.x;
  if (e >= 400 * 100) return;
  int i = e / 100, j = e - (e / 100) * 100;
  float s = 0.f;
#pragma unroll 4
  for (int k = 0; k < 200; ++k) s += W1[i * 200 + k] * W2[k * 100 + j];
  W[e] = s;
}

// ---------- Kernel B: Y[b] = x[b] @ W  (400x400 @ 400x100) ----------
__global__ __launch_bounds__(256) void kB(const float* __restrict__ x,
                                          const float* __restrict__ W,
                                          float* __restrict__ Y) {
  __shared__ float xs[16][41];
  __shared__ float ws[40][104];
  const int b = blockIdx.y, rt = blockIdx.x;
  const int tid = threadIdx.x;
  const int tc = tid & 31, tr = tid >> 5;
  const float* xb = x + (size_t)b * 160000 + (size_t)rt * 16 * 400;
  float acc[2][4] = {{0.f, 0.f, 0.f, 0.f}, {0.f, 0.f, 0.f, 0.f}};
  for (int k0 = 0; k0 < 400; k0 += 40) {
    for (int e = tid; e < 640; e += 256) {
      int r = e / 40, kk = e - r * 40;
      xs[r][kk] = xb[r * 400 + k0 + kk];
    }
    for (int e = tid; e < 4000; e += 256) {
      int kk = e / 100, j = e - kk * 100;
      ws[kk][j] = W[(k0 + kk) * 100 + j];
    }
    __syncthreads();
#pragma unroll 8
    for (int kk = 0; kk < 40; ++kk) {
      float a0 = xs[tr][kk], a1 = xs[tr + 8][kk];
      float b0 = ws[kk][tc], b1 = ws[kk][tc + 32], b2 = ws[kk][tc + 64];
      float b3 = (tc + 96 < 100) ? ws[kk][tc + 96] : 0.f;
      acc[0][0] += a0 * b0; acc[0][1] += a0 * b1; acc[0][2] += a0 * b2; acc[0][3] += a0 * b3;
      acc[1][0] += a1 * b0; acc[1][1] += a1 * b1; acc[1][2] += a1 * b2; acc[1][3] += a1 * b3;
    }
    __syncthreads();
  }
  float* Yb = Y + (size_t)b * 40000 + (size_t)rt * 1600;
#pragma unroll
  for (int rr = 0; rr < 2; ++rr) {
    int r = tr + 8 * rr;
#pragma unroll
    for (int u = 0; u < 4; ++u) {
      int c = tc + 32 * u;
      if (c < 100) Yb[r * 100 + c] = acc[rr][u];
    }
  }
}

// flat triu index (n=100) -> row (one-off use in symmetrize)
__device__ __forceinline__ int triu_row(int e) {
  int i = (int)((201.0f - sqrtf(40401.0f - 8.0f * (float)e)) * 0.5f);
  if (i < 0) i = 0;
  if (i > 99) i = 99;
  while (i > 0 && (201 * i - i * i) > 2 * e) --i;
  while ((201 * (i + 1) - (i + 1) * (i + 1)) <= 2 * e) ++i;
  return i;
}

// ---------- Kernel C: M = W^T Y_b ; logm via ONE-SIDED Jacobi ; classifier ----------
__global__ __launch_bounds__(1024) void kC(const float* __restrict__ W,
                                           const float* __restrict__ Y,
                                           const float* __restrict__ Wc,
                                           const float* __restrict__ bcv,
                                           float* __restrict__ out) {
  __shared__ float B[10000];      // column-major: column p at B + p*100
  __shared__ float stage[8320];   // GEMM staging; later Hf[5050]
  __shared__ float nrm[100];      // maintained squared column norms
  __shared__ float sfin[100];
  __shared__ float red[16][12];
  __shared__ float tstat[50];
  __shared__ int rotflag[50];
  __shared__ int brk;

  const int b = blockIdx.x, tid = threadIdx.x;
  const int g = tid >> 4, lane = tid & 15;  // 64 groups of 16 (wave-aligned)
  // 4x4 tile mapping for GEMM / H phases (625 active threads)
  const int r0 = tid / 25, c0 = tid - (tid / 25) * 25;

  // ---- M = W^T @ Y_b  into B : 4x4 register tiles, b128 LDS reads ----
  {
    float* Wst = stage;          // [40][104]
    float* Yst = stage + 4160;   // [40][104]
    const float* Yb = Y + (size_t)b * 40000;
    float acc[4][4];
#pragma unroll
    for (int a = 0; a < 4; ++a) acc[a][0] = acc[a][1] = acc[a][2] = acc[a][3] = 0.f;
    for (int k0 = 0; k0 < 400; k0 += 40) {
      for (int e = tid; e < 4000; e += 1024) {
        int kk = e / 100, j = e - kk * 100;
        Wst[kk * 104 + j] = W[(k0 + kk) * 100 + j];
        Yst[kk * 104 + j] = Yb[(k0 + kk) * 100 + j];
      }
      __syncthreads();        // uniform: all threads reach
      if (tid < 625) {
        for (int kk = 0; kk < 40; ++kk) {
          float4 w4 = *(const float4*)&Wst[kk * 104 + 4 * r0];
          float4 y4 = *(const float4*)&Yst[kk * 104 + 4 * c0];
          const float wv[4] = {w4.x, w4.y, w4.z, w4.w};
          const float yv[4] = {y4.x, y4.y, y4.z, y4.w};
#pragma unroll
          for (int a = 0; a < 4; ++a)
#pragma unroll
            for (int c = 0; c < 4; ++c) acc[a][c] += wv[a] * yv[c];
        }
      }
      __syncthreads();        // uniform: all threads reach
    }
    if (tid < 625) {
#pragma unroll
      for (int a = 0; a < 4; ++a) {
        float4 v = make_float4(acc[a][0], acc[a][1], acc[a][2], acc[a][3]);
        *(float4*)&B[(4 * r0 + a) * 100 + 4 * c0] = v;
      }
    }
  }
  if (tid < 50) { rotflag[tid] = 0; tstat[tid] = 0.f; }
  __syncthreads();
  // symmetrize both triangles
  for (int e = tid; e < 5050; e += 1024) {
    int i = triu_row(e);
    int j = i + (e - ((201 * i - i * i) >> 1));
    float av = 0.5f * (B[i * 100 + j] + B[j * 100 + i]);
    B[i * 100 + j] = av;
    B[j * 100 + i] = av;
  }
  __syncthreads();
  // initial squared norms (group g covers columns g, g+64)
  for (int col = g; col < 100; col += 64) {
    const float* bp = B + col * 100;
    float4 a4 = *(const float4*)(bp + 4 * lane);
    float n = a4.x * a4.x + a4.y * a4.y + a4.z * a4.z + a4.w * a4.w;
    if (lane < 9) {
      float4 a8 = *(const float4*)(bp + 64 + 4 * lane);
      n += a8.x * a8.x + a8.y * a8.y + a8.z * a8.z + a8.w * a8.w;
    }
    n = sum16(n);
    if (lane == 0) nrm[col] = n;
  }
  __syncthreads();

  // ---- one-sided cyclic Jacobi: fused dot+rotate, incremental schedule ----
  int p, q;
  if (g == 0) { p = 99; q = 0; }
  else { p = g; q = 99 - g; }
  int pp = p * 100, qq = q * 100;
  float tacc = 0.f;
  int any = 0;

  for (int r = 0; r < NRT; ++r) {
    const int rr = r % 99;
    if (g < 50) {
      float* bp = B + pp;
      float* bq = B + qq;
      float4 a4 = *(const float4*)(bp + 4 * lane);
      float4 b4 = *(const float4*)(bq + 4 * lane);
      float4 a8 = make_float4(0.f, 0.f, 0.f, 0.f), b8 = a8;
      float d = a4.x * b4.x + a4.y * b4.y + a4.z * b4.z + a4.w * b4.w;
      if (lane < 9) {
        a8 = *(const float4*)(bp + 64 + 4 * lane);
        b8 = *(const float4*)(bq + 64 + 4 * lane);
        d += a8.x * b8.x + a8.y * b8.y + a8.z * b8.z + a8.w * b8.w;
      }
      d = sum16(d);  // VALU DPP all-reduce
      float pn = nrm[p], qn = nrm[q];
      if (d * d > SKIPTH * pn * qn + 1e-30f) {  // group-uniform branch
        float tau = (qn - pn) / (2.f * d);
        float t = copysignf(1.f, tau) / (fabsf(tau) + sqrtf(1.f + tau * tau));
        float c = 1.f / sqrtf(1.f + t * t);
        float s = t * c;
        float4 n4, m4;
        n4.x = c * a4.x - s * b4.x; n4.y = c * a4.y - s * b4.y;
        n4.z = c * a4.z - s * b4.z; n4.w = c * a4.w - s * b4.w;
        m4.x = s * a4.x + c * b4.x; m4.y = s * a4.y + c * b4.y;
        m4.z = s * a4.z + c * b4.z; m4.w = s * a4.w + c * b4.w;
        *(float4*)(bp + 4 * lane) = n4;
        *(float4*)(bq + 4 * lane) = m4;
        if (lane < 9) {
          n4.x = c * a8.x - s * b8.x; n4.y = c * a8.y - s * b8.y;
          n4.z = c * a8.z - s * b8.z; n4.w = c * a8.w - s * b8.w;
          m4.x = s * a8.x + c * b8.x; m4.y = s * a8.y + c * b8.y;
          m4.z = s * a8.z + c * b8.z; m4.w = s * a8.w + c * b8.w;
          *(float4*)(bp + 64 + 4 * lane) = n4;
          *(float4*)(bq + 64 + 4 * lane) = m4;
        }
        tacc += t * t;
        any = 1;
        if (lane == 0) {
          nrm[p] = pn - t * d;   // exact Jacobi diagonal update
          nrm[q] = qn + t * d;
        }
      }
    }
    __syncthreads();
    // advance schedule incrementally (matches rr+1)
    ++q; qq += 100; if (q == 99) { q = 0; qq = 0; }
    if (g != 0) { ++p; pp += 100; if (p == 99) { p = 0; pp = 0; } }
    if (rr == 98) {  // sweep end: reduce rot flags + sum of t^2 (uniform branch)
      if (g < 50 && lane == 0) { rotflag[g] = any; tstat[g] = tacc; }
      any = 0; tacc = 0.f;
      __syncthreads();
      if (tid < 64) {
        int v = (tid < 50) ? rotflag[tid] : 0;
        float tv = (tid < 50) ? tstat[tid] : 0.f;
#pragma unroll
        for (int off = 32; off > 0; off >>= 1) {
          v += __shfl_xor(v, off);
          tv += __shfl_xor(tv, off);
        }
        if (tid == 0) brk = (v == 0 || tv < TAUBRK) ? 1 : 0;
      }
      __syncthreads();
      if (brk) break;
    }
  }

  // ---- exact final scales: sfin[p] = log(max(||b_p||,EPSV)) / ||b_p||^2 ----
  for (int col = g; col < 100; col += 64) {
    const float* bp = B + col * 100;
    float4 a4 = *(const float4*)(bp + 4 * lane);
    float n = a4.x * a4.x + a4.y * a4.y + a4.z * a4.z + a4.w * a4.w;
    if (lane < 9) {
      float4 a8 = *(const float4*)(bp + 64 + 4 * lane);
      n += a8.x * a8.x + a8.y * a8.y + a8.z * a8.z + a8.w * a8.w;
    }
    n = sum16(n);
    if (lane == 0) sfin[col] = logf(fmaxf(sqrtf(n), EPSV)) / n;
  }
  __syncthreads();

  // ---- Hf (triu flat) = sum_p sfin[p] * b_p b_p^T : 4x4 tiles, b128 reads ----
  // NO barrier inside divergent flow (round-13 bug): Hf aliases stage (dead),
  // B is read-only here, sfin synced above -> no internal ordering needed.
  float* Hf = stage;
  if (tid < 625) {
    float hacc[4][4];
#pragma unroll
    for (int a = 0; a < 4; ++a) hacc[a][0] = hacc[a][1] = hacc[a][2] = hacc[a][3] = 0.f;
    for (int pc = 0; pc < 100; ++pc) {
      const float* vr = B + pc * 100;
      float l = sfin[pc];
      float4 vi4 = *(const float4*)&vr[4 * r0];
      float4 vj4 = *(const float4*)&vr[4 * c0];
      const float vi[4] = {l * vi4.x, l * vi4.y, l * vi4.z, l * vi4.w};
      const float vj[4] = {vj4.x, vj4.y, vj4.z, vj4.w};
#pragma unroll
      for (int a = 0; a < 4; ++a)
#pragma unroll
        for (int c = 0; c < 4; ++c) hacc[a][c] += vi[a] * vj[c];
    }
#pragma unroll
    for (int a = 0; a < 4; ++a) {
      int i = 4 * r0 + a;
#pragma unroll
      for (int c = 0; c < 4; ++c) {
        int j = 4 * c0 + c;
        if (i <= j) Hf[((201 * i - i * i) >> 1) + (j - i)] = hacc[a][c];
      }
    }
  }
  __syncthreads();  // uniform: all threads reach

  // ---- classifier ----
  float accc[10];
#pragma unroll
  for (int c = 0; c < 10; ++c) accc[c] = 0.f;
  for (int e = tid; e < 5050; e += 1024) {
    float h = Hf[e];
#pragma unroll
    for (int c = 0; c < 10; ++c) accc[c] += h * Wc[c * 5050 + e];
  }
  const int lane64 = tid & 63, wv = tid >> 6;
#pragma unroll
  for (int c = 0; c < 10; ++c) {
    float v = accc[c];
#pragma unroll
    for (int off = 32; off > 0; off >>= 1) v += __shfl_down(v, off);
    if (lane64 == 0) red[wv][c] = v;
  }
  __syncthreads();
  if (tid < 10) {
    float s = bcv[tid];
#pragma unroll
    for (int w = 0; w < 16; ++w) s += red[w][tid];
    out[b * 10 + tid] = s;
  }
}

extern "C" void kernel_launch(void* const* d_in, const int* in_sizes, int n_in,
                              void* d_out, int out_size, void* d_ws, size_t ws_size,
                              hipStream_t stream) {
  const float* x = (const float*)d_in[0];
  const float* W1 = (const float*)d_in[1];
  const float* W2 = (const float*)d_in[2];
  const float* Wc = (const float*)d_in[3];
  const float* bc = (const float*)d_in[4];
  float* out = (float*)d_out;

  float* W = (float*)d_ws;        // 400*100 floats
  float* Y = W + 40000;           // 256*400*100 floats (~41 MB)

  kA<<<157, 256, 0, stream>>>(W1, W2, W);
  kB<<<dim3(25, 256), 256, 0, stream>>>(x, W, Y);
  kC<<<256, 1024, 0, stream>>>(W, Y, Wc, bc, out);
}

// Round 15
// 1204.600 us; speedup vs baseline: 1.6443x; 1.0107x over previous
//
#include <hip/hip_runtime.h>
#include <math.h>

#define EPSV 1e-4f
#define NSWEEP 10
#define NRT (99 * NSWEEP)
#define SKIPTH 4e-8f
#define TAUBRK 5e-3f

// ---------- 16-lane all-reduce sum on the VALU (DPP), no LDS pipe ----------
template <int CTRL>
__device__ __forceinline__ float dppadd(float x) {
  int y = __builtin_amdgcn_update_dpp(0, __float_as_int(x), CTRL, 0xF, 0xF, false);
  return x + __int_as_float(y);
}
__device__ __forceinline__ float sum16(float x) {
  x = dppadd<0xB1>(x);   // quad_perm [1,0,3,2]  == xor 1
  x = dppadd<0x4E>(x);   // quad_perm [2,3,0,1]  == xor 2
  x = dppadd<0x124>(x);  // row_ror:4
  x = dppadd<0x128>(x);  // row_ror:8
  return x;
}

// ---------- Kernel A: W = W1 @ W2 (400x200 @ 200x100 -> 400x100) ----------
__global__ __launch_bounds__(256) void kA(const float* __restrict__ W1,
                                          const float* __restrict__ W2,
                                          float* __restrict__ W) {
  int e = blockIdx.x * 256 + threadIdx.x;
  if (e >= 400 * 100) return;
  int i = e / 100, j = e - (e / 100) * 100;
  float s = 0.f;
#pragma unroll 4
  for (int k = 0; k < 200; ++k) s += W1[i * 200 + k] * W2[k * 100 + j];
  W[e] = s;
}

// ---------- Kernel B: Y[b] = x[b] @ W  (400x400 @ 400x100) ----------
__global__ __launch_bounds__(256) void kB(const float* __restrict__ x,
                                          const float* __restrict__ W,
                                          float* __restrict__ Y) {
  __shared__ float xs[16][41];
  __shared__ float ws[40][104];
  const int b = blockIdx.y, rt = blockIdx.x;
  const int tid = threadIdx.x;
  const int tc = tid & 31, tr = tid >> 5;
  const float* xb = x + (size_t)b * 160000 + (size_t)rt * 16 * 400;
  float acc[2][4] = {{0.f, 0.f, 0.f, 0.f}, {0.f, 0.f, 0.f, 0.f}};
  for (int k0 = 0; k0 < 400; k0 += 40) {
    for (int e = tid; e < 640; e += 256) {
      int r = e / 40, kk = e - r * 40;
      xs[r][kk] = xb[r * 400 + k0 + kk];
    }
    for (int e = tid; e < 4000; e += 256) {
      int kk = e / 100, j = e - kk * 100;
      ws[kk][j] = W[(k0 + kk) * 100 + j];
    }
    __syncthreads();
#pragma unroll 8
    for (int kk = 0; kk < 40; ++kk) {
      float a0 = xs[tr][kk], a1 = xs[tr + 8][kk];
      float b0 = ws[kk][tc], b1 = ws[kk][tc + 32], b2 = ws[kk][tc + 64];
      float b3 = (tc + 96 < 100) ? ws[kk][tc + 96] : 0.f;
      acc[0][0] += a0 * b0; acc[0][1] += a0 * b1; acc[0][2] += a0 * b2; acc[0][3] += a0 * b3;
      acc[1][0] += a1 * b0; acc[1][1] += a1 * b1; acc[1][2] += a1 * b2; acc[1][3] += a1 * b3;
    }
    __syncthreads();
  }
  float* Yb = Y + (size_t)b * 40000 + (size_t)rt * 1600;
#pragma unroll
  for (int rr = 0; rr < 2; ++rr) {
    int r = tr + 8 * rr;
#pragma unroll
    for (int u = 0; u < 4; ++u) {
      int c = tc + 32 * u;
      if (c < 100) Yb[r * 100 + c] = acc[rr][u];
    }
  }
}

// flat triu index (n=100) -> row (one-off use in symmetrize)
__device__ __forceinline__ int triu_row(int e) {
  int i = (int)((201.0f - sqrtf(40401.0f - 8.0f * (float)e)) * 0.5f);
  if (i < 0) i = 0;
  if (i > 99) i = 99;
  while (i > 0 && (201 * i - i * i) > 2 * e) --i;
  while ((201 * (i + 1) - (i + 1) * (i + 1)) <= 2 * e) ++i;
  return i;
}

// ---------- Kernel C: M = W^T Y_b ; logm via ONE-SIDED Jacobi ; classifier ----------
__global__ __launch_bounds__(1024) void kC(const float* __restrict__ W,
                                           const float* __restrict__ Y,
                                           const float* __restrict__ Wc,
                                           const float* __restrict__ bcv,
                                           float* __restrict__ out) {
  __shared__ float B[10000];      // column-major: column p at B + p*100
  __shared__ float stage[8320];   // GEMM staging; later Hf[5050]
  __shared__ float nrm[100];      // maintained squared column norms
  __shared__ float sfin[100];
  __shared__ float red[16][12];
  __shared__ float tstat[50];
  __shared__ int rotflag[50];
  __shared__ int brk;

  const int b = blockIdx.x, tid = threadIdx.x;
  const int g = tid >> 4, lane = tid & 15;  // 64 groups of 16 (wave-aligned)
  // 4x4 tile mapping for GEMM / H phases (625 active threads)
  const int r0 = tid / 25, c0 = tid - (tid / 25) * 25;

  // ---- M = W^T @ Y_b  into B : 4x4 register tiles, b128 LDS reads ----
  {
    float* Wst = stage;          // [40][104]
    float* Yst = stage + 4160;   // [40][104]
    const float* Yb = Y + (size_t)b * 40000;
    float acc[4][4];
#pragma unroll
    for (int a = 0; a < 4; ++a) acc[a][0] = acc[a][1] = acc[a][2] = acc[a][3] = 0.f;
    for (int k0 = 0; k0 < 400; k0 += 40) {
      for (int e = tid; e < 4000; e += 1024) {
        int kk = e / 100, j = e - kk * 100;
        Wst[kk * 104 + j] = W[(k0 + kk) * 100 + j];
        Yst[kk * 104 + j] = Yb[(k0 + kk) * 100 + j];
      }
      __syncthreads();        // uniform: all threads reach
      if (tid < 625) {
        for (int kk = 0; kk < 40; ++kk) {
          float4 w4 = *(const float4*)&Wst[kk * 104 + 4 * r0];
          float4 y4 = *(const float4*)&Yst[kk * 104 + 4 * c0];
          const float wv[4] = {w4.x, w4.y, w4.z, w4.w};
          const float yv[4] = {y4.x, y4.y, y4.z, y4.w};
#pragma unroll
          for (int a = 0; a < 4; ++a)
#pragma unroll
            for (int c = 0; c < 4; ++c) acc[a][c] += wv[a] * yv[c];
        }
      }
      __syncthreads();        // uniform: all threads reach
    }
    if (tid < 625) {
#pragma unroll
      for (int a = 0; a < 4; ++a) {
        float4 v = make_float4(acc[a][0], acc[a][1], acc[a][2], acc[a][3]);
        *(float4*)&B[(4 * r0 + a) * 100 + 4 * c0] = v;
      }
    }
  }
  if (tid < 50) { rotflag[tid] = 0; tstat[tid] = 0.f; }
  __syncthreads();
  // symmetrize both triangles
  for (int e = tid; e < 5050; e += 1024) {
    int i = triu_row(e);
    int j = i + (e - ((201 * i - i * i) >> 1));
    float av = 0.5f * (B[i * 100 + j] + B[j * 100 + i]);
    B[i * 100 + j] = av;
    B[j * 100 + i] = av;
  }
  __syncthreads();
  // initial squared norms (group g covers columns g, g+64)
  for (int col = g; col < 100; col += 64) {
    const float* bp = B + col * 100;
    float4 a4 = *(const float4*)(bp + 4 * lane);
    float n = a4.x * a4.x + a4.y * a4.y + a4.z * a4.z + a4.w * a4.w;
    if (lane < 9) {
      float4 a8 = *(const float4*)(bp + 64 + 4 * lane);
      n += a8.x * a8.x + a8.y * a8.y + a8.z * a8.z + a8.w * a8.w;
    }
    n = sum16(n);
    if (lane == 0) nrm[col] = n;
  }
  __syncthreads();

  // ---- one-sided cyclic Jacobi: fused dot+rotate, incremental schedule ----
  int p, q;
  if (g == 0) { p = 99; q = 0; }
  else { p = g; q = 99 - g; }
  int pp = p * 100, qq = q * 100;
  float tacc = 0.f;
  int any = 0;

  for (int r = 0; r < NRT; ++r) {
    const int rr = r % 99;
    if (g < 50) {
      float* bp = B + pp;
      float* bq = B + qq;
      float4 a4 = *(const float4*)(bp + 4 * lane);
      float4 b4 = *(const float4*)(bq + 4 * lane);
      float4 a8 = make_float4(0.f, 0.f, 0.f, 0.f), b8 = a8;
      float d = a4.x * b4.x + a4.y * b4.y + a4.z * b4.z + a4.w * b4.w;
      if (lane < 9) {
        a8 = *(const float4*)(bp + 64 + 4 * lane);
        b8 = *(const float4*)(bq + 64 + 4 * lane);
        d += a8.x * b8.x + a8.y * b8.y + a8.z * b8.z + a8.w * b8.w;
      }
      d = sum16(d);  // VALU DPP all-reduce
      float pn = nrm[p], qn = nrm[q];
      if (d * d > SKIPTH * pn * qn + 1e-30f) {  // group-uniform branch
        float tau = (qn - pn) / (2.f * d);
        float t = copysignf(1.f, tau) / (fabsf(tau) + sqrtf(1.f + tau * tau));
        float c = 1.f / sqrtf(1.f + t * t);
        float s = t * c;
        float4 n4, m4;
        n4.x = c * a4.x - s * b4.x; n4.y = c * a4.y - s * b4.y;
        n4.z = c * a4.z - s * b4.z; n4.w = c * a4.w - s * b4.w;
        m4.x = s * a4.x + c * b4.x; m4.y = s * a4.y + c * b4.y;
        m4.z = s * a4.z + c * b4.z; m4.w = s * a4.w + c * b4.w;
        *(float4*)(bp + 4 * lane) = n4;
        *(float4*)(bq + 4 * lane) = m4;
        if (lane < 9) {
          n4.x = c * a8.x - s * b8.x; n4.y = c * a8.y - s * b8.y;
          n4.z = c * a8.z - s * b8.z; n4.w = c * a8.w - s * b8.w;
          m4.x = s * a8.x + c * b8.x; m4.y = s * a8.y + c * b8.y;
          m4.z = s * a8.z + c * b8.z; m4.w = s * a8.w + c * b8.w;
          *(float4*)(bp + 64 + 4 * lane) = n4;
          *(float4*)(bq + 64 + 4 * lane) = m4;
        }
        tacc += t * t;
        any = 1;
        if (lane == 0) {
          nrm[p] = pn - t * d;   // exact Jacobi diagonal update
          nrm[q] = qn + t * d;
        }
      }
    }
    __syncthreads();
    // advance schedule incrementally (matches rr+1)
    ++q; qq += 100; if (q == 99) { q = 0; qq = 0; }
    if (g != 0) { ++p; pp += 100; if (p == 99) { p = 0; pp = 0; } }
    if (rr == 98) {  // sweep end: reduce rot flags + sum of t^2 (uniform branch)
      if (g < 50 && lane == 0) { rotflag[g] = any; tstat[g] = tacc; }
      any = 0; tacc = 0.f;
      __syncthreads();
      if (tid < 64) {
        int v = (tid < 50) ? rotflag[tid] : 0;
        float tv = (tid < 50) ? tstat[tid] : 0.f;
#pragma unroll
        for (int off = 32; off > 0; off >>= 1) {
          v += __shfl_xor(v, off);
          tv += __shfl_xor(tv, off);
        }
        if (tid == 0) brk = (v == 0 || tv < TAUBRK) ? 1 : 0;
      }
      __syncthreads();
      if (brk) break;
    }
  }

  // ---- exact final scales: sfin[p] = log(max(||b_p||,EPSV)) / ||b_p||^2 ----
  for (int col = g; col < 100; col += 64) {
    const float* bp = B + col * 100;
    float4 a4 = *(const float4*)(bp + 4 * lane);
    float n = a4.x * a4.x + a4.y * a4.y + a4.z * a4.z + a4.w * a4.w;
    if (lane < 9) {
      float4 a8 = *(const float4*)(bp + 64 + 4 * lane);
      n += a8.x * a8.x + a8.y * a8.y + a8.z * a8.z + a8.w * a8.w;
    }
    n = sum16(n);
    if (lane == 0) sfin[col] = logf(fmaxf(sqrtf(n), EPSV)) / n;
  }
  __syncthreads();

  // ---- Hf (triu flat) = sum_p sfin[p] * b_p b_p^T : 4x4 tiles, b128 reads ----
  // NO barrier inside divergent flow: Hf aliases stage (dead), B read-only here.
  float* Hf = stage;
  if (tid < 625) {
    float hacc[4][4];
#pragma unroll
    for (int a = 0; a < 4; ++a) hacc[a][0] = hacc[a][1] = hacc[a][2] = hacc[a][3] = 0.f;
    for (int pc = 0; pc < 100; ++pc) {
      const float* vr = B + pc * 100;
      float l = sfin[pc];
      float4 vi4 = *(const float4*)&vr[4 * r0];
      float4 vj4 = *(const float4*)&vr[4 * c0];
      const float vi[4] = {l * vi4.x, l * vi4.y, l * vi4.z, l * vi4.w};
      const float vj[4] = {vj4.x, vj4.y, vj4.z, vj4.w};
#pragma unroll
      for (int a = 0; a < 4; ++a)
#pragma unroll
        for (int c = 0; c < 4; ++c) hacc[a][c] += vi[a] * vj[c];
    }
#pragma unroll
    for (int a = 0; a < 4; ++a) {
      int i = 4 * r0 + a;
#pragma unroll
      for (int c = 0; c < 4; ++c) {
        int j = 4 * c0 + c;
        if (i <= j) Hf[((201 * i - i * i) >> 1) + (j - i)] = hacc[a][c];
      }
    }
  }
  __syncthreads();  // uniform: all threads reach

  // ---- classifier ----
  float accc[10];
#pragma unroll
  for (int c = 0; c < 10; ++c) accc[c] = 0.f;
  for (int e = tid; e < 5050; e += 1024) {
    float h = Hf[e];
#pragma unroll
    for (int c = 0; c < 10; ++c) accc[c] += h * Wc[c * 5050 + e];
  }
  const int lane64 = tid & 63, wv = tid >> 6;
#pragma unroll
  for (int c = 0; c < 10; ++c) {
    float v = accc[c];
#pragma unroll
    for (int off = 32; off > 0; off >>= 1) v += __shfl_down(v, off);
    if (lane64 == 0) red[wv][c] = v;
  }
  __syncthreads();
  if (tid < 10) {
    float s = bcv[tid];
#pragma unroll
    for (int w = 0; w < 16; ++w) s += red[w][tid];
    out[b * 10 + tid] = s;
  }
}

extern "C" void kernel_launch(void* const* d_in, const int* in_sizes, int n_in,
                              void* d_out, int out_size, void* d_ws, size_t ws_size,
                              hipStream_t stream) {
  const float* x = (const float*)d_in[0];
  const float* W1 = (const float*)d_in[1];
  const float* W2 = (const float*)d_in[2];
  const float* Wc = (const float*)d_in[3];
  const float* bc = (const float*)d_in[4];
  float* out = (float*)d_out;

  float* W = (float*)d_ws;        // 400*100 floats
  float* Y = W + 40000;           // 256*400*100 floats (~41 MB)

  kA<<<157, 256, 0, stream>>>(W1, W2, W);
  kB<<<dim3(25, 256), 256, 0, stream>>>(x, W, Y);
  kC<<<256, 1024, 0, stream>>>(W, Y, Wc, bc, out);
}

// Round 16
// 1072.966 us; speedup vs baseline: 1.8460x; 1.1227x over previous
//
#include <hip/hip_runtime.h>
#include <math.h>

#define EPSV 1e-4f
#define NSWEEP 10
#define NRT (99 * NSWEEP)
#define SKIPTH 4e-8f
#define TAUBRK 5e-3f

// ---------- 16-lane all-reduce sum on the VALU (DPP), no LDS pipe ----------
template <int CTRL>
__device__ __forceinline__ float dppadd(float x) {
  int y = __builtin_amdgcn_update_dpp(0, __float_as_int(x), CTRL, 0xF, 0xF, false);
  return x + __int_as_float(y);
}
__device__ __forceinline__ float sum16(float x) {
  x = dppadd<0xB1>(x);   // quad_perm [1,0,3,2]  == xor 1
  x = dppadd<0x4E>(x);   // quad_perm [2,3,0,1]  == xor 2
  x = dppadd<0x124>(x);  // row_ror:4
  x = dppadd<0x128>(x);  // row_ror:8
  return x;
}

// ---------- Kernel A: W = W1 @ W2 (400x200 @ 200x100 -> 400x100) ----------
__global__ __launch_bounds__(256) void kA(const float* __restrict__ W1,
                                          const float* __restrict__ W2,
                                          float* __restrict__ W) {
  int e = blockIdx.x * 256 + threadIdx.x;
  if (e >= 400 * 100) return;
  int i = e / 100, j = e - (e / 100) * 100;
  float s = 0.f;
#pragma unroll 4
  for (int k = 0; k < 200; ++k) s += W1[i * 200 + k] * W2[k * 100 + j];
  W[e] = s;
}

// ---------- Kernel B: Y[b] = x[b] @ W : 40x100 tile/block, 4x4 reg tiles, b128 LDS ----
__global__ __launch_bounds__(256) void kB(const float* __restrict__ x,
                                          const float* __restrict__ W,
                                          float* __restrict__ Y) {
  __shared__ __align__(16) float xsT[40 * 40];   // [kk][row], pitch 40 (160B, 16B-aligned)
  __shared__ __align__(16) float ws[40 * 104];   // [kk][col], pitch 104 (416B, 16B-aligned)
  const int b = blockIdx.y, rt = blockIdx.x;     // rt in [0,10): rows rt*40..rt*40+39
  const int tid = threadIdx.x;
  const int r0 = tid / 25, c0 = tid - (tid / 25) * 25;  // valid when tid<250
  const float* xb = x + (size_t)b * 160000 + (size_t)rt * 40 * 400;
  float acc[4][4];
#pragma unroll
  for (int a = 0; a < 4; ++a) acc[a][0] = acc[a][1] = acc[a][2] = acc[a][3] = 0.f;
  for (int k0 = 0; k0 < 400; k0 += 40) {
    // stage x^T (transposed) and W
    for (int e = tid; e < 1600; e += 256) {
      int r = e / 40, kk = e - r * 40;
      xsT[kk * 40 + r] = xb[r * 400 + k0 + kk];
    }
    for (int e = tid; e < 4000; e += 256) {
      int kk = e / 100, j = e - kk * 100;
      ws[kk * 104 + j] = W[(k0 + kk) * 100 + j];
    }
    __syncthreads();
    if (tid < 250) {
      for (int kk = 0; kk < 40; ++kk) {
        float4 x4 = *(const float4*)&xsT[kk * 40 + 4 * r0];
        float4 w4 = *(const float4*)&ws[kk * 104 + 4 * c0];
        const float xv[4] = {x4.x, x4.y, x4.z, x4.w};
        const float wv[4] = {w4.x, w4.y, w4.z, w4.w};
#pragma unroll
        for (int a = 0; a < 4; ++a)
#pragma unroll
          for (int c = 0; c < 4; ++c) acc[a][c] += xv[a] * wv[c];
      }
    }
    __syncthreads();
  }
  if (tid < 250) {
    float* Yb = Y + (size_t)b * 40000 + ((size_t)rt * 40 + 4 * r0) * 100 + 4 * c0;
#pragma unroll
    for (int a = 0; a < 4; ++a) {
      float4 v = make_float4(acc[a][0], acc[a][1], acc[a][2], acc[a][3]);
      *(float4*)(Yb + a * 100) = v;
    }
  }
}

// flat triu index (n=100) -> row (one-off use in symmetrize)
__device__ __forceinline__ int triu_row(int e) {
  int i = (int)((201.0f - sqrtf(40401.0f - 8.0f * (float)e)) * 0.5f);
  if (i < 0) i = 0;
  if (i > 99) i = 99;
  while (i > 0 && (201 * i - i * i) > 2 * e) --i;
  while ((201 * (i + 1) - (i + 1) * (i + 1)) <= 2 * e) ++i;
  return i;
}

// ---------- Kernel C: M = W^T Y_b ; logm via ONE-SIDED Jacobi ; classifier ----------
__global__ __launch_bounds__(1024) void kC(const float* __restrict__ W,
                                           const float* __restrict__ Y,
                                           const float* __restrict__ Wc,
                                           const float* __restrict__ bcv,
                                           float* __restrict__ out) {
  __shared__ float B[10000];      // column-major: column p at B + p*100
  __shared__ float stage[8320];   // GEMM staging; later Hf[5050]
  __shared__ float nrm[100];      // maintained squared column norms
  __shared__ float sfin[100];
  __shared__ float red[16][12];
  __shared__ float tstat[50];
  __shared__ int rotflag[50];
  __shared__ int brk;

  const int b = blockIdx.x, tid = threadIdx.x;
  const int g = tid >> 4, lane = tid & 15;  // 64 groups of 16 (wave-aligned)
  // 4x4 tile mapping for GEMM / H phases (625 active threads)
  const int r0 = tid / 25, c0 = tid - (tid / 25) * 25;

  // ---- M = W^T @ Y_b  into B : 4x4 register tiles, b128 LDS reads ----
  {
    float* Wst = stage;          // [40][104]
    float* Yst = stage + 4160;   // [40][104]
    const float* Yb = Y + (size_t)b * 40000;
    float acc[4][4];
#pragma unroll
    for (int a = 0; a < 4; ++a) acc[a][0] = acc[a][1] = acc[a][2] = acc[a][3] = 0.f;
    for (int k0 = 0; k0 < 400; k0 += 40) {
      for (int e = tid; e < 4000; e += 1024) {
        int kk = e / 100, j = e - kk * 100;
        Wst[kk * 104 + j] = W[(k0 + kk) * 100 + j];
        Yst[kk * 104 + j] = Yb[(k0 + kk) * 100 + j];
      }
      __syncthreads();        // uniform: all threads reach
      if (tid < 625) {
        for (int kk = 0; kk < 40; ++kk) {
          float4 w4 = *(const float4*)&Wst[kk * 104 + 4 * r0];
          float4 y4 = *(const float4*)&Yst[kk * 104 + 4 * c0];
          const float wv[4] = {w4.x, w4.y, w4.z, w4.w};
          const float yv[4] = {y4.x, y4.y, y4.z, y4.w};
#pragma unroll
          for (int a = 0; a < 4; ++a)
#pragma unroll
            for (int c = 0; c < 4; ++c) acc[a][c] += wv[a] * yv[c];
        }
      }
      __syncthreads();        // uniform: all threads reach
    }
    if (tid < 625) {
#pragma unroll
      for (int a = 0; a < 4; ++a) {
        float4 v = make_float4(acc[a][0], acc[a][1], acc[a][2], acc[a][3]);
        *(float4*)&B[(4 * r0 + a) * 100 + 4 * c0] = v;
      }
    }
  }
  if (tid < 50) { rotflag[tid] = 0; tstat[tid] = 0.f; }
  __syncthreads();
  // symmetrize both triangles
  for (int e = tid; e < 5050; e += 1024) {
    int i = triu_row(e);
    int j = i + (e - ((201 * i - i * i) >> 1));
    float av = 0.5f * (B[i * 100 + j] + B[j * 100 + i]);
    B[i * 100 + j] = av;
    B[j * 100 + i] = av;
  }
  __syncthreads();
  // initial squared norms (group g covers columns g, g+64)
  for (int col = g; col < 100; col += 64) {
    const float* bp = B + col * 100;
    float4 a4 = *(const float4*)(bp + 4 * lane);
    float n = a4.x * a4.x + a4.y * a4.y + a4.z * a4.z + a4.w * a4.w;
    if (lane < 9) {
      float4 a8 = *(const float4*)(bp + 64 + 4 * lane);
      n += a8.x * a8.x + a8.y * a8.y + a8.z * a8.z + a8.w * a8.w;
    }
    n = sum16(n);
    if (lane == 0) nrm[col] = n;
  }
  __syncthreads();

  // ---- one-sided cyclic Jacobi: fused dot+rotate, incremental schedule ----
  int p, q;
  if (g == 0) { p = 99; q = 0; }
  else { p = g; q = 99 - g; }
  int pp = p * 100, qq = q * 100;
  float tacc = 0.f;
  int any = 0;

  for (int r = 0; r < NRT; ++r) {
    const int rr = r % 99;
    if (g < 50) {
      float* bp = B + pp;
      float* bq = B + qq;
      float4 a4 = *(const float4*)(bp + 4 * lane);
      float4 b4 = *(const float4*)(bq + 4 * lane);
      float4 a8 = make_float4(0.f, 0.f, 0.f, 0.f), b8 = a8;
      float d = a4.x * b4.x + a4.y * b4.y + a4.z * b4.z + a4.w * b4.w;
      if (lane < 9) {
        a8 = *(const float4*)(bp + 64 + 4 * lane);
        b8 = *(const float4*)(bq + 64 + 4 * lane);
        d += a8.x * b8.x + a8.y * b8.y + a8.z * b8.z + a8.w * b8.w;
      }
      d = sum16(d);  // VALU DPP all-reduce
      float pn = nrm[p], qn = nrm[q];
      if (d * d > SKIPTH * pn * qn + 1e-30f) {  // group-uniform branch
        float tau = (qn - pn) / (2.f * d);
        float t = copysignf(1.f, tau) / (fabsf(tau) + sqrtf(1.f + tau * tau));
        float c = 1.f / sqrtf(1.f + t * t);
        float s = t * c;
        float4 n4, m4;
        n4.x = c * a4.x - s * b4.x; n4.y = c * a4.y - s * b4.y;
        n4.z = c * a4.z - s * b4.z; n4.w = c * a4.w - s * b4.w;
        m4.x = s * a4.x + c * b4.x; m4.y = s * a4.y + c * b4.y;
        m4.z = s * a4.z + c * b4.z; m4.w = s * a4.w + c * b4.w;
        *(float4*)(bp + 4 * lane) = n4;
        *(float4*)(bq + 4 * lane) = m4;
        if (lane < 9) {
          n4.x = c * a8.x - s * b8.x; n4.y = c * a8.y - s * b8.y;
          n4.z = c * a8.z - s * b8.z; n4.w = c * a8.w - s * b8.w;
          m4.x = s * a8.x + c * b8.x; m4.y = s * a8.y + c * b8.y;
          m4.z = s * a8.z + c * b8.z; m4.w = s * a8.w + c * b8.w;
          *(float4*)(bp + 64 + 4 * lane) = n4;
          *(float4*)(bq + 64 + 4 * lane) = m4;
        }
        tacc += t * t;
        any = 1;
        if (lane == 0) {
          nrm[p] = pn - t * d;   // exact Jacobi diagonal update
          nrm[q] = qn + t * d;
        }
      }
    }
    __syncthreads();
    // advance schedule incrementally (matches rr+1)
    ++q; qq += 100; if (q == 99) { q = 0; qq = 0; }
    if (g != 0) { ++p; pp += 100; if (p == 99) { p = 0; pp = 0; } }
    if (rr == 98) {  // sweep end: reduce rot flags + sum of t^2 (uniform branch)
      if (g < 50 && lane == 0) { rotflag[g] = any; tstat[g] = tacc; }
      any = 0; tacc = 0.f;
      __syncthreads();
      if (tid < 64) {
        int v = (tid < 50) ? rotflag[tid] : 0;
        float tv = (tid < 50) ? tstat[tid] : 0.f;
#pragma unroll
        for (int off = 32; off > 0; off >>= 1) {
          v += __shfl_xor(v, off);
          tv += __shfl_xor(tv, off);
        }
        if (tid == 0) brk = (v == 0 || tv < TAUBRK) ? 1 : 0;
      }
      __syncthreads();
      if (brk) break;
    }
  }

  // ---- exact final scales: sfin[p] = log(max(||b_p||,EPSV)) / ||b_p||^2 ----
  for (int col = g; col < 100; col += 64) {
    const float* bp = B + col * 100;
    float4 a4 = *(const float4*)(bp + 4 * lane);
    float n = a4.x * a4.x + a4.y * a4.y + a4.z * a4.z + a4.w * a4.w;
    if (lane < 9) {
      float4 a8 = *(const float4*)(bp + 64 + 4 * lane);
      n += a8.x * a8.x + a8.y * a8.y + a8.z * a8.z + a8.w * a8.w;
    }
    n = sum16(n);
    if (lane == 0) sfin[col] = logf(fmaxf(sqrtf(n), EPSV)) / n;
  }
  __syncthreads();

  // ---- Hf (triu flat) = sum_p sfin[p] * b_p b_p^T : 4x4 tiles, b128 reads ----
  // NO barrier inside divergent flow: Hf aliases stage (dead), B read-only here.
  float* Hf = stage;
  if (tid < 625) {
    float hacc[4][4];
#pragma unroll
    for (int a = 0; a < 4; ++a) hacc[a][0] = hacc[a][1] = hacc[a][2] = hacc[a][3] = 0.f;
    for (int pc = 0; pc < 100; ++pc) {
      const float* vr = B + pc * 100;
      float l = sfin[pc];
      float4 vi4 = *(const float4*)&vr[4 * r0];
      float4 vj4 = *(const float4*)&vr[4 * c0];
      const float vi[4] = {l * vi4.x, l * vi4.y, l * vi4.z, l * vi4.w};
      const float vj[4] = {vj4.x, vj4.y, vj4.z, vj4.w};
#pragma unroll
      for (int a = 0; a < 4; ++a)
#pragma unroll
        for (int c = 0; c < 4; ++c) hacc[a][c] += vi[a] * vj[c];
    }
#pragma unroll
    for (int a = 0; a < 4; ++a) {
      int i = 4 * r0 + a;
#pragma unroll
      for (int c = 0; c < 4; ++c) {
        int j = 4 * c0 + c;
        if (i <= j) Hf[((201 * i - i * i) >> 1) + (j - i)] = hacc[a][c];
      }
    }
  }
  __syncthreads();  // uniform: all threads reach

  // ---- classifier ----
  float accc[10];
#pragma unroll
  for (int c = 0; c < 10; ++c) accc[c] = 0.f;
  for (int e = tid; e < 5050; e += 1024) {
    float h = Hf[e];
#pragma unroll
    for (int c = 0; c < 10; ++c) accc[c] += h * Wc[c * 5050 + e];
  }
  const int lane64 = tid & 63, wv = tid >> 6;
#pragma unroll
  for (int c = 0; c < 10; ++c) {
    float v = accc[c];
#pragma unroll
    for (int off = 32; off > 0; off >>= 1) v += __shfl_down(v, off);
    if (lane64 == 0) red[wv][c] = v;
  }
  __syncthreads();
  if (tid < 10) {
    float s = bcv[tid];
#pragma unroll
    for (int w = 0; w < 16; ++w) s += red[w][tid];
    out[b * 10 + tid] = s;
  }
}

extern "C" void kernel_launch(void* const* d_in, const int* in_sizes, int n_in,
                              void* d_out, int out_size, void* d_ws, size_t ws_size,
                              hipStream_t stream) {
  const float* x = (const float*)d_in[0];
  const float* W1 = (const float*)d_in[1];
  const float* W2 = (const float*)d_in[2];
  const float* Wc = (const float*)d_in[3];
  const float* bc = (const float*)d_in[4];
  float* out = (float*)d_out;

  float* W = (float*)d_ws;        // 400*100 floats
  float* Y = W + 40000;           // 256*400*100 floats (~41 MB)

  kA<<<157, 256, 0, stream>>>(W1, W2, W);
  kB<<<dim3(10, 256), 256, 0, stream>>>(x, W, Y);
  kC<<<256, 1024, 0, stream>>>(W, Y, Wc, bc, out);
}